// Round 1
// baseline (2583.269 us; speedup 1.0000x reference)
//
#include <hip/hip_runtime.h>
#include <math.h>

// ---------------------------------------------------------------------------
// Model constants
// ---------------------------------------------------------------------------
#define BB 4
#define SS 1024
#define LL 4
#define HH 8
#define DM 512
#define DF 2048
#define DH 64
#define NS 5
#define RR 32
#define MM 128          // favor feature dims
#define NC 16           // attention chunks
#define CHK 64          // chunk size

#define INV_SQRT10   0.316227766016838f
#define INV_SCALE    0.148650889375340f   // 1/(R*DH)^0.25 = 1/2048^0.25
#define TEMP_SCALE   0.353553390593274f   // 64^-0.25
#define INV_SQRT_M   0.088388347648318f   // 1/sqrt(128)
#define TWO_PI       6.283185307179586f

// ---------------------------------------------------------------------------
// GEMM: C[M,N] = A[M,K] @ B[K,N] + bias (optionally relu). M,N,K % 64 == 0.
// 64x64 tile, BK=16, 256 threads, 4x4 per thread.
// ---------------------------------------------------------------------------
template<int RELU>
__global__ __launch_bounds__(256)
void gemm_bias(const float* __restrict__ A, const float* __restrict__ B,
               const float* __restrict__ bias, float* __restrict__ C,
               int M, int N, int K)
{
  __shared__ float As[16][68];
  __shared__ float Bs[16][68];
  const int tid = threadIdx.x;
  const int tx = tid & 15;         // n dir
  const int ty = tid >> 4;         // m dir
  const int row0 = blockIdx.y * 64;
  const int col0 = blockIdx.x * 64;
  const int am = tid >> 2;         // 0..63
  const int ak = (tid & 3) * 4;    // 0,4,8,12
  const int bk = tid >> 4;         // 0..15
  const int bn = (tid & 15) * 4;   // 0..60
  float acc[4][4] = {};
  for (int k0 = 0; k0 < K; k0 += 16) {
    const float4 av = *reinterpret_cast<const float4*>(&A[(size_t)(row0 + am) * K + (k0 + ak)]);
    const float4 bv = *reinterpret_cast<const float4*>(&B[(size_t)(k0 + bk) * N + (col0 + bn)]);
    As[ak + 0][am] = av.x;
    As[ak + 1][am] = av.y;
    As[ak + 2][am] = av.z;
    As[ak + 3][am] = av.w;
    *reinterpret_cast<float4*>(&Bs[bk][bn]) = bv;
    __syncthreads();
#pragma unroll
    for (int kk = 0; kk < 16; ++kk) {
      const float4 a = *reinterpret_cast<const float4*>(&As[kk][ty * 4]);
      const float4 b = *reinterpret_cast<const float4*>(&Bs[kk][tx * 4]);
      acc[0][0] += a.x * b.x; acc[0][1] += a.x * b.y; acc[0][2] += a.x * b.z; acc[0][3] += a.x * b.w;
      acc[1][0] += a.y * b.x; acc[1][1] += a.y * b.y; acc[1][2] += a.y * b.z; acc[1][3] += a.y * b.w;
      acc[2][0] += a.z * b.x; acc[2][1] += a.z * b.y; acc[2][2] += a.z * b.z; acc[2][3] += a.z * b.w;
      acc[3][0] += a.w * b.x; acc[3][1] += a.w * b.y; acc[3][2] += a.w * b.z; acc[3][3] += a.w * b.w;
    }
    __syncthreads();
  }
#pragma unroll
  for (int j = 0; j < 4; ++j) {
    const int row = row0 + ty * 4 + j;
#pragma unroll
    for (int i = 0; i < 4; ++i) {
      const int col = col0 + tx * 4 + i;
      float v = acc[j][i] + bias[col];
      if (RELU) v = fmaxf(v, 0.f);
      C[(size_t)row * N + col] = v;
    }
  }
}

// ---------------------------------------------------------------------------
// SPE precompute (per layer):
//   zp[h][d][k][r] = noise * softplus(gains)_up / sqrt(10) * sqrt(1-sig(gate)) / scale
//   wb[h][d][r]    = sqrt(sig(gate)) * gate_noise / scale
// ---------------------------------------------------------------------------
__global__ __launch_bounds__(256)
void spe_prep(const float* __restrict__ gains, const float* __restrict__ noise,
              const float* __restrict__ gate, const float* __restrict__ gnoise,
              float* __restrict__ zp, float* __restrict__ wb)
{
  const int i = blockIdx.x * 256 + threadIdx.x;
  if (i < HH * DH * 2 * NS * RR) {           // 163840
    const int hd = i / (2 * NS * RR);        // h*64+d
    const int k  = (i >> 5) % (2 * NS);
    const float ga = gains[hd * NS + (k >> 1)];
    const float sp = (ga > 20.f) ? ga : log1pf(expf(ga));
    const float gg = 1.f / (1.f + expf(-gate[hd]));
    const float c1 = sqrtf(fmaxf(1.f - gg, 0.f));
    zp[i] = noise[i] * sp * c1 * (INV_SQRT10 * INV_SCALE);
  } else {
    const int j = i - HH * DH * 2 * NS * RR;
    if (j < HH * DH * RR) {                  // 16384
      const int hd = j >> 5;
      const float gg = 1.f / (1.f + expf(-gate[hd]));
      wb[j] = sqrtf(gg) * gnoise[j] * INV_SCALE;
    }
  }
}

// ---------------------------------------------------------------------------
// Fused SineSPE filter + FAVOR feature map. One block per (s,h).
// q,k: (B,S,H,DH). Outputs Qf,Kf: (B,S,H,M).
// ---------------------------------------------------------------------------
__global__ __launch_bounds__(256)
void spe_favor(const float* __restrict__ freqs, const float* __restrict__ offs,
               const float* __restrict__ zp, const float* __restrict__ wb,
               const float* __restrict__ q, const float* __restrict__ k,
               const float* __restrict__ omega,
               float* __restrict__ Qf, float* __restrict__ Kf)
{
  const int s = blockIdx.x;
  const int h = blockIdx.y;
  const int t = threadIdx.x;
  __shared__ float omq[DH][2 * NS];
  __shared__ float omk[DH][2 * NS];
  __shared__ float qb[DH][64];
  __shared__ float kb[DH][64];
  __shared__ float rowsQ[BB][DH];
  __shared__ float rowsK[BB][DH];
  __shared__ float xq[BB][64];
  __shared__ float xk[BB][64];

  // 1) sine phases
  for (int e = t; e < DH * NS; e += 256) {
    const int d = e / NS, ns = e % NS;
    const float fr = 0.5f / (1.f + expf(-freqs[(h * DH + d) * NS + ns]));
    const float phk = TWO_PI * fr * (float)s;
    const float phq = phk + offs[(h * DH + d) * NS + ns];
    float sn, cn;
    sincosf(phk, &sn, &cn);
    omk[d][2 * ns] = cn; omk[d][2 * ns + 1] = sn;
    sincosf(phq, &sn, &cn);
    omq[d][2 * ns] = cn; omq[d][2 * ns + 1] = sn;
  }
  // 3) q/k rows (same barrier region as step 2)
  {
    const int b = t >> 6, d = t & 63;
    const size_t idx = (((size_t)b * SS + s) * HH + h) * DH + d;
    rowsQ[b][d] = q[idx];
    rowsK[b][d] = k[idx];
  }
  __syncthreads();
  // 2) build qb/kb (first 32 cols from sines*z, last 32 = shared bias)
  for (int e = t; e < DH * RR; e += 256) {
    const int d = e >> 5, r = e & 31;
    const float* zrow = zp + ((size_t)(h * DH + d) * 2 * NS) * RR + r;
    float aq = 0.f, ak2 = 0.f;
#pragma unroll
    for (int kk = 0; kk < 2 * NS; ++kk) {
      const float zv = zrow[(size_t)kk * RR];
      aq  += omq[d][kk] * zv;
      ak2 += omk[d][kk] * zv;
    }
    qb[d][r] = aq;
    kb[d][r] = ak2;
    const float wv = wb[(h * DH + d) * RR + r];
    qb[d][32 + r] = wv;
    kb[d][32 + r] = wv;
  }
  __syncthreads();
  // 4) qhat/khat (scaled by temp)
  {
    const int b = t >> 6, r = t & 63;
    float aq = 0.f, ak2 = 0.f;
#pragma unroll
    for (int d = 0; d < DH; ++d) {
      aq  += rowsQ[b][d] * qb[d][r];
      ak2 += rowsK[b][d] * kb[d][r];
    }
    xq[b][r] = aq * TEMP_SCALE;
    xk[b][r] = ak2 * TEMP_SCALE;
  }
  __syncthreads();
  // 5) half-norms, u = x @ omega, exp outputs
  {
    const int b = t >> 6, m = t & 63;
    float hq = 0.f, hk = 0.f;
#pragma unroll
    for (int e = 0; e < 64; ++e) {
      const float a = xq[b][e]; hq += a * a;
      const float c = xk[b][e]; hk += c * c;
    }
    hq *= 0.5f; hk *= 0.5f;
    float uq = 0.f, uk = 0.f;
#pragma unroll
    for (int e = 0; e < 64; ++e) {
      const float w = omega[e * 64 + m];
      uq += xq[b][e] * w;
      uk += xk[b][e] * w;
    }
    const size_t ob = (((size_t)b * SS + s) * HH + h) * MM + m;
    Qf[ob]      = expf( uq - hq) * INV_SQRT_M;
    Qf[ob + 64] = expf(-uq - hq) * INV_SQRT_M;
    Kf[ob]      = expf( uk - hk) * INV_SQRT_M;
    Kf[ob + 64] = expf(-uk - hk) * INV_SQRT_M;
  }
}

// ---------------------------------------------------------------------------
// Attention pass A: per-chunk sums  Sch[b,h,c][m][d] = sum_t k[t][m] v[t][d]
//                                    kch[b,h,c][m]   = sum_t k[t][m]
// ---------------------------------------------------------------------------
__global__ __launch_bounds__(256)
void attn_chunk_sums(const float* __restrict__ Kf, const float* __restrict__ V,
                     float* __restrict__ Sch, float* __restrict__ kch)
{
  const int c = blockIdx.x, h = blockIdx.y, b = blockIdx.z;
  const int t = threadIdx.x;
  __shared__ float Kc[CHK][MM];
  __shared__ float Vc[CHK][DH];
  for (int e = t; e < CHK * MM; e += 256) {
    const int row = e >> 7, m = e & 127;
    Kc[row][m] = Kf[(((size_t)b * SS + c * CHK + row) * HH + h) * MM + m];
  }
  for (int e = t; e < CHK * DH; e += 256) {
    const int row = e >> 6, d = e & 63;
    Vc[row][d] = V[(((size_t)b * SS + c * CHK + row) * HH + h) * DH + d];
  }
  __syncthreads();
  const int m = t >> 1;
  const int d0 = (t & 1) * 32;
  float acc[32] = {};
  float ks = 0.f;
  for (int r = 0; r < CHK; ++r) {
    const float kv = Kc[r][m];
    ks += kv;
#pragma unroll
    for (int j = 0; j < 32; ++j) acc[j] += kv * Vc[r][d0 + j];
  }
  const size_t base = ((size_t)b * HH + h) * NC + c;
  float* So = Sch + base * (MM * DH) + (size_t)m * DH + d0;
#pragma unroll
  for (int j = 0; j < 32; ++j) So[j] = acc[j];
  if ((t & 1) == 0) kch[base * MM + m] = ks;
}

// ---------------------------------------------------------------------------
// Attention pass B: in-place exclusive scan over chunks per (b,h)
// ---------------------------------------------------------------------------
__global__ __launch_bounds__(256)
void attn_scan(float* __restrict__ Sch, float* __restrict__ kch)
{
  const int bh = blockIdx.x;
  const int t = threadIdx.x;
  float* base = Sch + (size_t)bh * NC * (MM * DH);
  for (int e = t; e < MM * DH; e += 256) {
    float run = 0.f;
#pragma unroll
    for (int c = 0; c < NC; ++c) {
      const float v = base[(size_t)c * (MM * DH) + e];
      base[(size_t)c * (MM * DH) + e] = run;
      run += v;
    }
  }
  float* kb2 = kch + (size_t)bh * NC * MM;
  if (t < MM) {
    float run = 0.f;
#pragma unroll
    for (int c = 0; c < NC; ++c) {
      const float v = kb2[c * MM + t];
      kb2[c * MM + t] = run;
      run += v;
    }
  }
}

// ---------------------------------------------------------------------------
// Attention pass C: out[s][d] = (Q@Sprev + tril(QK^T)V) / (q.(skprev+cumk)+eps)
// One block per (b,h,c). att written in (B,S,DM) layout.
// ---------------------------------------------------------------------------
__global__ __launch_bounds__(256)
void attn_out(const float* __restrict__ Qf, const float* __restrict__ Kf,
              const float* __restrict__ V, const float* __restrict__ Sch,
              const float* __restrict__ kch, float* __restrict__ att)
{
  const int c = blockIdx.x, h = blockIdx.y, b = blockIdx.z;
  const int t = threadIdx.x;
  __shared__ float KV[CHK][MM];       // Kc in phase 1, Vc (first 64 cols) in phase 2
  __shared__ float Abuf[CHK][CHK + 1];
  __shared__ float denl[CHK];
  __shared__ float skp[MM];
  const size_t srow0 = (size_t)b * SS + c * CHK;

  for (int e = t; e < CHK * MM; e += 256) {
    const int row = e >> 7, m = e & 127;
    KV[row][m] = Kf[((srow0 + row) * HH + h) * MM + m];
  }
  if (t < MM) skp[t] = kch[(((size_t)b * HH + h) * NC + c) * MM + t];
  __syncthreads();

  const int s = t & 63;
  const int grp = t >> 6;            // 0..3
  const int tb = grp * 16;
  const float* qrow = Qf + ((srow0 + s) * HH + h) * MM;

  // phase 1: A[s][tb..tb+15]
  float a[16];
#pragma unroll
  for (int j = 0; j < 16; ++j) a[j] = 0.f;
  for (int mc = 0; mc < MM; mc += 16) {
    float qv[16];
#pragma unroll
    for (int i = 0; i < 16; ++i) qv[i] = qrow[mc + i];
#pragma unroll
    for (int j = 0; j < 16; ++j) {
      float p = 0.f;
#pragma unroll
      for (int i = 0; i < 16; ++i) p += qv[i] * KV[tb + j][mc + i];
      a[j] += p;
    }
  }
#pragma unroll
  for (int j = 0; j < 16; ++j) Abuf[s][tb + j] = a[j];
  __syncthreads();

  // load Vc over the Kc region
  for (int e = t; e < CHK * DH; e += 256) {
    const int row = e >> 6, d = e & 63;
    KV[row][d] = V[((srow0 + row) * HH + h) * DH + d];
  }
  __syncthreads();

  // phase 2: masked intra + den
  const int dg = grp * 16;
  float num[16];
#pragma unroll
  for (int j = 0; j < 16; ++j) num[j] = 0.f;
  float den = 0.f;
  for (int tt = 0; tt <= s; ++tt) {
    const float av = Abuf[s][tt];
    den += av;
#pragma unroll
    for (int j = 0; j < 16; ++j) num[j] += av * KV[tt][dg + j];
  }
  if (t < 64) {
    float dq = 0.f;
#pragma unroll
    for (int m = 0; m < MM; ++m) dq += qrow[m] * skp[m];
    denl[s] = den + dq + 1e-6f;
  }
  // inter: Q @ Sprev
  const float* Sp = Sch + (((size_t)b * HH + h) * NC + c) * (MM * DH);
  for (int m = 0; m < MM; ++m) {
    const float qv = qrow[m];
#pragma unroll
    for (int j = 0; j < 16; ++j) num[j] += qv * Sp[(size_t)m * DH + dg + j];
  }
  __syncthreads();
  const float dinv = 1.f / denl[s];
  float* op = att + (srow0 + s) * DM + h * DH + dg;
#pragma unroll
  for (int j = 0; j < 16; ++j) op[j] = num[j] * dinv;
}

// ---------------------------------------------------------------------------
// out = LayerNorm(a + b) * g + beta   (row width 512)
// ---------------------------------------------------------------------------
__global__ __launch_bounds__(256)
void add_ln(const float* __restrict__ a, const float* __restrict__ bres,
            const float* __restrict__ g, const float* __restrict__ be,
            float* __restrict__ out)
{
  const int row = blockIdx.x;
  const int t = threadIdx.x;
  const size_t base = (size_t)row * DM;
  const float x0 = a[base + t] + bres[base + t];
  const float x1 = a[base + t + 256] + bres[base + t + 256];
  __shared__ float red[8];
  float ssum = x0 + x1;
#pragma unroll
  for (int off = 32; off > 0; off >>= 1) ssum += __shfl_xor(ssum, off, 64);
  const int wid = t >> 6, lid = t & 63;
  if (lid == 0) red[wid] = ssum;
  __syncthreads();
  const float mu = (red[0] + red[1] + red[2] + red[3]) * (1.f / DM);
  const float d0 = x0 - mu, d1 = x1 - mu;
  float sv = d0 * d0 + d1 * d1;
#pragma unroll
  for (int off = 32; off > 0; off >>= 1) sv += __shfl_xor(sv, off, 64);
  if (lid == 0) red[4 + wid] = sv;
  __syncthreads();
  const float var = (red[4] + red[5] + red[6] + red[7]) * (1.f / DM);
  const float rs = rsqrtf(var + 1e-5f);
  out[base + t]       = d0 * rs * g[t]       + be[t];
  out[base + t + 256] = d1 * rs * g[t + 256] + be[t + 256];
}

// ---------------------------------------------------------------------------
// Host-side launch
// ---------------------------------------------------------------------------
extern "C" void kernel_launch(void* const* d_in, const int* in_sizes, int n_in,
                              void* d_out, int out_size, void* d_ws, size_t ws_size,
                              hipStream_t stream)
{
  const float* x      = (const float*)d_in[0];
  const float* Wq     = (const float*)d_in[1];
  const float* bq     = (const float*)d_in[2];
  const float* Wk     = (const float*)d_in[3];
  const float* bk     = (const float*)d_in[4];
  const float* Wv     = (const float*)d_in[5];
  const float* bv     = (const float*)d_in[6];
  const float* Wo     = (const float*)d_in[7];
  const float* bo     = (const float*)d_in[8];
  const float* W1     = (const float*)d_in[9];
  const float* b1     = (const float*)d_in[10];
  const float* W2     = (const float*)d_in[11];
  const float* b2     = (const float*)d_in[12];
  const float* ln1g   = (const float*)d_in[13];
  const float* ln1b   = (const float*)d_in[14];
  const float* ln2g   = (const float*)d_in[15];
  const float* ln2b   = (const float*)d_in[16];
  const float* freqs  = (const float*)d_in[17];
  const float* offs   = (const float*)d_in[18];
  const float* gains  = (const float*)d_in[19];
  const float* noise  = (const float*)d_in[20];
  const float* gate   = (const float*)d_in[21];
  const float* gnoise = (const float*)d_in[22];
  const float* omega  = (const float*)d_in[23];

  float* ws = (float*)d_ws;
  size_t o = 0;
  float* cur  = ws + o; o += (size_t)BB * SS * DM;        // 2M
  float* qbuf = ws + o; o += (size_t)BB * SS * DM;        // q  / later y
  float* kbuf = ws + o; o += (size_t)BB * SS * DM;        // k  / later att@Wo
  float* vbuf = ws + o; o += (size_t)BB * SS * DM;        // v  / later h
  float* Qf   = ws + o; o += (size_t)BB * SS * HH * MM;   // 4M \ contiguous 8M
  float* Kf   = ws + o; o += (size_t)BB * SS * HH * MM;   // 4M /  = FFN mid
  float* attb = ws + o; o += (size_t)BB * SS * DM;        // 2M
  float* Sch  = ws + o; o += (size_t)BB * HH * NC * MM * DH;  // 4M
  float* kch  = ws + o; o += (size_t)BB * HH * NC * MM;       // 64K
  float* zp   = ws + o; o += (size_t)HH * DH * 2 * NS * RR;   // 160K
  float* wbf  = ws + o; o += (size_t)HH * DH * RR;            // 16K
  float* mid  = Qf;     // 8M contiguous (Qf+Kf)
  float* ybuf = qbuf;
  float* attp = kbuf;
  float* hbuf = vbuf;

  for (int l = 0; l < LL; ++l) {
    const float* in = (l == 0) ? x : cur;

    spe_prep<<<704, 256, 0, stream>>>(gains + (size_t)l * HH * DH * NS,
                                      noise + (size_t)l * HH * DH * 2 * NS * RR,
                                      gate + (size_t)l * HH * DH,
                                      gnoise + (size_t)l * HH * DH * RR, zp, wbf);

    gemm_bias<0><<<dim3(8, 64), 256, 0, stream>>>(in, Wq + (size_t)l * DM * DM, bq + (size_t)l * DM, qbuf, BB * SS, DM, DM);
    gemm_bias<0><<<dim3(8, 64), 256, 0, stream>>>(in, Wk + (size_t)l * DM * DM, bk + (size_t)l * DM, kbuf, BB * SS, DM, DM);
    gemm_bias<0><<<dim3(8, 64), 256, 0, stream>>>(in, Wv + (size_t)l * DM * DM, bv + (size_t)l * DM, vbuf, BB * SS, DM, DM);

    spe_favor<<<dim3(SS, HH), 256, 0, stream>>>(freqs + (size_t)l * HH * DH * NS,
                                                offs + (size_t)l * HH * DH * NS,
                                                zp, wbf, qbuf, kbuf,
                                                omega + (size_t)l * DH * (MM / 2), Qf, Kf);

    attn_chunk_sums<<<dim3(NC, HH, BB), 256, 0, stream>>>(Kf, vbuf, Sch, kch);
    attn_scan<<<BB * HH, 256, 0, stream>>>(Sch, kch);
    attn_out<<<dim3(NC, HH, BB), 256, 0, stream>>>(Qf, Kf, vbuf, Sch, kch, attb);

    gemm_bias<0><<<dim3(8, 64), 256, 0, stream>>>(attb, Wo + (size_t)l * DM * DM, bo + (size_t)l * DM, attp, BB * SS, DM, DM);
    add_ln<<<BB * SS, 256, 0, stream>>>(in, attp, ln1g + (size_t)l * DM, ln1b + (size_t)l * DM, hbuf);

    gemm_bias<1><<<dim3(32, 64), 256, 0, stream>>>(hbuf, W1 + (size_t)l * DM * DF, b1 + (size_t)l * DF, mid, BB * SS, DF, DM);
    gemm_bias<0><<<dim3(8, 64), 256, 0, stream>>>(mid, W2 + (size_t)l * DF * DM, b2 + (size_t)l * DM, ybuf, BB * SS, DM, DF);

    float* dst = (l == LL - 1) ? (float*)d_out : cur;
    add_ln<<<BB * SS, 256, 0, stream>>>(hbuf, ybuf, ln2g + (size_t)l * DM, ln2b + (size_t)l * DM, dst);
  }
}

// Round 2
// 1339.298 us; speedup vs baseline: 1.9288x; 1.9288x over previous
//
#include <hip/hip_runtime.h>
#include <math.h>

// ---------------------------------------------------------------------------
// Model constants
// ---------------------------------------------------------------------------
#define BB 4
#define SS 1024
#define LL 4
#define HH 8
#define DM 512
#define DF 2048
#define DH 64
#define NS 5
#define RR 32
#define MM 128          // favor feature dims
#define NC 16           // attention chunks
#define CHK 64          // chunk size
#define QKV_N 1536      // packed q|k|v width

#define INV_SQRT10   0.316227766016838f
#define INV_SCALE    0.148650889375340f   // 1/(R*DH)^0.25
#define TEMP_SCALE   0.353553390593274f   // 64^-0.25
#define INV_SQRT_M   0.088388347648318f   // 1/sqrt(128)
#define TWO_PI       6.283185307179586f

typedef __attribute__((ext_vector_type(8))) short bf16x8;
typedef __attribute__((ext_vector_type(4))) float f32x4;

__device__ __forceinline__ unsigned short f2bf(float f) {
  union { float f; unsigned int u; } v; v.f = f;
  unsigned int r = v.u + 0x7FFFu + ((v.u >> 16) & 1u);
  return (unsigned short)(r >> 16);
}

__device__ __forceinline__ void gld_lds16(const unsigned short* g, unsigned short* l) {
  __builtin_amdgcn_global_load_lds((const __attribute__((address_space(1))) void*)g,
                                   (__attribute__((address_space(3))) void*)l,
                                   16, 0, 0);
}

// ---------------------------------------------------------------------------
// bf16 MFMA GEMM (m97 structure): C[M,N] = A[M,K] @ Bt[N,K]^T + bias.
// A: bf16 row-major [M][K]; Bt: bf16 [N][K]. 128x128 tile, BK=32, 4 waves.
// OUT_BF=0 -> f32 C; OUT_BF=1 -> bf16 C.
// ---------------------------------------------------------------------------
template<int RELU, int OUT_BF>
__global__ __launch_bounds__(256)
void gemm_mfma(const unsigned short* __restrict__ A, const unsigned short* __restrict__ Bt,
               const float* __restrict__ bias, float* __restrict__ Cf,
               unsigned short* __restrict__ Cbf, int M, int N, int K)
{
  __shared__ unsigned short As[128 * 32];   // [m][k]
  __shared__ unsigned short Bs[128 * 32];   // [n][k]
  const int tid  = threadIdx.x;
  const int w    = tid >> 6;
  const int lane = tid & 63;
  const int row0 = blockIdx.y * 128;
  const int col0 = blockIdx.x * 128;
  const int wr = (w >> 1) * 64;
  const int wc = (w & 1) * 64;
  // staging: chunk c (0..7) covers flat elems [c*512, c*512+512): m=flat>>5, k=flat&31
  const int c0 = w * 2, c1 = w * 2 + 1;
  const int m0 = c0 * 16 + (lane >> 2);
  const int m1 = c1 * 16 + (lane >> 2);
  const int kA = (lane & 3) * 8;

  f32x4 acc[4][4] = {};

  for (int k0 = 0; k0 < K; k0 += 32) {
    gld_lds16(&A [(size_t)(row0 + m0) * K + k0 + kA], &As[c0 * 512]);
    gld_lds16(&A [(size_t)(row0 + m1) * K + k0 + kA], &As[c1 * 512]);
    gld_lds16(&Bt[(size_t)(col0 + m0) * K + k0 + kA], &Bs[c0 * 512]);
    gld_lds16(&Bt[(size_t)(col0 + m1) * K + k0 + kA], &Bs[c1 * 512]);
    __syncthreads();
    const int rA = wr + (lane & 15);
    const int rB = wc + (lane & 15);
    const int kk = (lane >> 4) * 8;
    bf16x8 af[4], bfr[4];
#pragma unroll
    for (int i = 0; i < 4; ++i) {
      af[i]  = *reinterpret_cast<const bf16x8*>(&As[(rA + i * 16) * 32 + kk]);
      bfr[i] = *reinterpret_cast<const bf16x8*>(&Bs[(rB + i * 16) * 32 + kk]);
    }
#pragma unroll
    for (int mi = 0; mi < 4; ++mi)
#pragma unroll
      for (int ni = 0; ni < 4; ++ni)
        acc[mi][ni] = __builtin_amdgcn_mfma_f32_16x16x32_bf16(af[mi], bfr[ni], acc[mi][ni], 0, 0, 0);
    __syncthreads();
  }
  // epilogue: C/D layout col=lane&15, row=(lane>>4)*4+reg
  const int cr = (lane >> 4) * 4;
  const int cc = lane & 15;
#pragma unroll
  for (int mi = 0; mi < 4; ++mi) {
#pragma unroll
    for (int ni = 0; ni < 4; ++ni) {
      const int col = col0 + wc + ni * 16 + cc;
      const float bv = bias[col];
#pragma unroll
      for (int r = 0; r < 4; ++r) {
        const int row = row0 + wr + mi * 16 + cr + r;
        float v = acc[mi][ni][r] + bv;
        if (RELU) v = fmaxf(v, 0.f);
        if (OUT_BF) Cbf[(size_t)row * N + col] = f2bf(v);
        else        Cf [(size_t)row * N + col] = v;
      }
    }
  }
}

// ---------------------------------------------------------------------------
// Transpose + f32->bf16: W[K][N] -> Wt[N][K]
// ---------------------------------------------------------------------------
__global__ __launch_bounds__(256)
void transpose_bf(const float* __restrict__ W, unsigned short* __restrict__ Wt, int K, int N)
{
  __shared__ float tile[32][33];
  const int k0 = blockIdx.y * 32, n0 = blockIdx.x * 32;
  const int tx = threadIdx.x & 31, ty = threadIdx.x >> 5;  // 8 rows
#pragma unroll
  for (int j = 0; j < 4; ++j)
    tile[ty + 8 * j][tx] = W[(size_t)(k0 + ty + 8 * j) * N + n0 + tx];
  __syncthreads();
#pragma unroll
  for (int j = 0; j < 4; ++j)
    Wt[(size_t)(n0 + ty + 8 * j) * K + k0 + tx] = f2bf(tile[tx][ty + 8 * j]);
}

__global__ __launch_bounds__(256)
void pack_bias(const float* __restrict__ bq, const float* __restrict__ bk,
               const float* __restrict__ bv, float* __restrict__ out)
{
  const int i = blockIdx.x * 256 + threadIdx.x;
  if (i < QKV_N) out[i] = (i < 512) ? bq[i] : (i < 1024) ? bk[i - 512] : bv[i - 1024];
}

__global__ __launch_bounds__(256)
void cvt_bf16(const float* __restrict__ in, unsigned short* __restrict__ out, int n4)
{
  const int i = blockIdx.x * 256 + threadIdx.x;
  if (i < n4) {
    const float4 v = reinterpret_cast<const float4*>(in)[i];
    ushort4 o;
    o.x = f2bf(v.x); o.y = f2bf(v.y); o.z = f2bf(v.z); o.w = f2bf(v.w);
    reinterpret_cast<ushort4*>(out)[i] = o;
  }
}

// ---------------------------------------------------------------------------
// SPE precompute (unchanged)
// ---------------------------------------------------------------------------
__global__ __launch_bounds__(256)
void spe_prep(const float* __restrict__ gains, const float* __restrict__ noise,
              const float* __restrict__ gate, const float* __restrict__ gnoise,
              float* __restrict__ zp, float* __restrict__ wb)
{
  const int i = blockIdx.x * 256 + threadIdx.x;
  if (i < HH * DH * 2 * NS * RR) {
    const int hd = i / (2 * NS * RR);
    const int k  = (i >> 5) % (2 * NS);
    const float ga = gains[hd * NS + (k >> 1)];
    const float sp = (ga > 20.f) ? ga : log1pf(expf(ga));
    const float gg = 1.f / (1.f + expf(-gate[hd]));
    const float c1 = sqrtf(fmaxf(1.f - gg, 0.f));
    zp[i] = noise[i] * sp * c1 * (INV_SQRT10 * INV_SCALE);
  } else {
    const int j = i - HH * DH * 2 * NS * RR;
    if (j < HH * DH * RR) {
      const int hd = j >> 5;
      const float gg = 1.f / (1.f + expf(-gate[hd]));
      wb[j] = sqrtf(gg) * gnoise[j] * INV_SCALE;
    }
  }
}

// ---------------------------------------------------------------------------
// Fused SineSPE filter + FAVOR. q/k read from packed qkv (stride 1536).
// ---------------------------------------------------------------------------
__global__ __launch_bounds__(256)
void spe_favor(const float* __restrict__ freqs, const float* __restrict__ offs,
               const float* __restrict__ zp, const float* __restrict__ wb,
               const float* __restrict__ qkv, const float* __restrict__ omega,
               float* __restrict__ Qf, float* __restrict__ Kf)
{
  const int s = blockIdx.x;
  const int h = blockIdx.y;
  const int t = threadIdx.x;
  __shared__ float omq[DH][2 * NS];
  __shared__ float omk[DH][2 * NS];
  __shared__ float qb[DH][64];
  __shared__ float kb[DH][64];
  __shared__ float rowsQ[BB][DH];
  __shared__ float rowsK[BB][DH];
  __shared__ float xq[BB][64];
  __shared__ float xk[BB][64];

  for (int e = t; e < DH * NS; e += 256) {
    const int d = e / NS, ns = e % NS;
    const float fr = 0.5f / (1.f + expf(-freqs[(h * DH + d) * NS + ns]));
    const float phk = TWO_PI * fr * (float)s;
    const float phq = phk + offs[(h * DH + d) * NS + ns];
    float sn, cn;
    sincosf(phk, &sn, &cn);
    omk[d][2 * ns] = cn; omk[d][2 * ns + 1] = sn;
    sincosf(phq, &sn, &cn);
    omq[d][2 * ns] = cn; omq[d][2 * ns + 1] = sn;
  }
  {
    const int b = t >> 6, d = t & 63;
    const size_t idx = ((size_t)b * SS + s) * QKV_N + h * DH + d;
    rowsQ[b][d] = qkv[idx];
    rowsK[b][d] = qkv[idx + 512];
  }
  __syncthreads();
  for (int e = t; e < DH * RR; e += 256) {
    const int d = e >> 5, r = e & 31;
    const float* zrow = zp + ((size_t)(h * DH + d) * 2 * NS) * RR + r;
    float aq = 0.f, ak2 = 0.f;
#pragma unroll
    for (int kk = 0; kk < 2 * NS; ++kk) {
      const float zv = zrow[(size_t)kk * RR];
      aq  += omq[d][kk] * zv;
      ak2 += omk[d][kk] * zv;
    }
    qb[d][r] = aq;
    kb[d][r] = ak2;
    const float wv = wb[(h * DH + d) * RR + r];
    qb[d][32 + r] = wv;
    kb[d][32 + r] = wv;
  }
  __syncthreads();
  {
    const int b = t >> 6, r = t & 63;
    float aq = 0.f, ak2 = 0.f;
#pragma unroll
    for (int d = 0; d < DH; ++d) {
      aq  += rowsQ[b][d] * qb[d][r];
      ak2 += rowsK[b][d] * kb[d][r];
    }
    xq[b][r] = aq * TEMP_SCALE;
    xk[b][r] = ak2 * TEMP_SCALE;
  }
  __syncthreads();
  {
    const int b = t >> 6, m = t & 63;
    float hq = 0.f, hk = 0.f;
#pragma unroll
    for (int e = 0; e < 64; ++e) {
      const float a = xq[b][e]; hq += a * a;
      const float c = xk[b][e]; hk += c * c;
    }
    hq *= 0.5f; hk *= 0.5f;
    float uq = 0.f, uk = 0.f;
#pragma unroll
    for (int e = 0; e < 64; ++e) {
      const float w2 = omega[e * 64 + m];
      uq += xq[b][e] * w2;
      uk += xk[b][e] * w2;
    }
    const size_t ob = (((size_t)b * SS + s) * HH + h) * MM + m;
    Qf[ob]      = expf( uq - hq) * INV_SQRT_M;
    Qf[ob + 64] = expf(-uq - hq) * INV_SQRT_M;
    Kf[ob]      = expf( uk - hk) * INV_SQRT_M;
    Kf[ob + 64] = expf(-uk - hk) * INV_SQRT_M;
  }
}

// ---------------------------------------------------------------------------
// Attention pass A (V from packed qkv)
// ---------------------------------------------------------------------------
__global__ __launch_bounds__(256)
void attn_chunk_sums(const float* __restrict__ Kf, const float* __restrict__ qkv,
                     float* __restrict__ Sch, float* __restrict__ kch)
{
  const int c = blockIdx.x, h = blockIdx.y, b = blockIdx.z;
  const int t = threadIdx.x;
  __shared__ float Kc[CHK][MM];
  __shared__ float Vc[CHK][DH];
  for (int e = t; e < CHK * MM; e += 256) {
    const int row = e >> 7, m = e & 127;
    Kc[row][m] = Kf[(((size_t)b * SS + c * CHK + row) * HH + h) * MM + m];
  }
  for (int e = t; e < CHK * DH; e += 256) {
    const int row = e >> 6, d = e & 63;
    Vc[row][d] = qkv[((size_t)b * SS + c * CHK + row) * QKV_N + 1024 + h * DH + d];
  }
  __syncthreads();
  const int m = t >> 1;
  const int d0 = (t & 1) * 32;
  float acc[32] = {};
  float ks = 0.f;
  for (int r = 0; r < CHK; ++r) {
    const float kv = Kc[r][m];
    ks += kv;
#pragma unroll
    for (int j = 0; j < 32; ++j) acc[j] += kv * Vc[r][d0 + j];
  }
  const size_t base = ((size_t)b * HH + h) * NC + c;
  float* So = Sch + base * (MM * DH) + (size_t)m * DH + d0;
#pragma unroll
  for (int j = 0; j < 32; ++j) So[j] = acc[j];
  if ((t & 1) == 0) kch[base * MM + m] = ks;
}

// ---------------------------------------------------------------------------
// Attention pass B (unchanged)
// ---------------------------------------------------------------------------
__global__ __launch_bounds__(256)
void attn_scan(float* __restrict__ Sch, float* __restrict__ kch)
{
  const int bh = blockIdx.x;
  const int t = threadIdx.x;
  float* base = Sch + (size_t)bh * NC * (MM * DH);
  for (int e = t; e < MM * DH; e += 256) {
    float run = 0.f;
#pragma unroll
    for (int c = 0; c < NC; ++c) {
      const float v = base[(size_t)c * (MM * DH) + e];
      base[(size_t)c * (MM * DH) + e] = run;
      run += v;
    }
  }
  float* kb2 = kch + (size_t)bh * NC * MM;
  if (t < MM) {
    float run = 0.f;
#pragma unroll
    for (int c = 0; c < NC; ++c) {
      const float v = kb2[c * MM + t];
      kb2[c * MM + t] = run;
      run += v;
    }
  }
}

// ---------------------------------------------------------------------------
// Attention pass C: writes att in bf16 (B,S,DM) for the Wo GEMM.
// ---------------------------------------------------------------------------
__global__ __launch_bounds__(256)
void attn_out(const float* __restrict__ Qf, const float* __restrict__ Kf,
              const float* __restrict__ qkv, const float* __restrict__ Sch,
              const float* __restrict__ kch, unsigned short* __restrict__ att)
{
  const int c = blockIdx.x, h = blockIdx.y, b = blockIdx.z;
  const int t = threadIdx.x;
  __shared__ float KV[CHK][MM];
  __shared__ float Abuf[CHK][CHK + 1];
  __shared__ float denl[CHK];
  __shared__ float skp[MM];
  const size_t srow0 = (size_t)b * SS + c * CHK;

  for (int e = t; e < CHK * MM; e += 256) {
    const int row = e >> 7, m = e & 127;
    KV[row][m] = Kf[((srow0 + row) * HH + h) * MM + m];
  }
  if (t < MM) skp[t] = kch[(((size_t)b * HH + h) * NC + c) * MM + t];
  __syncthreads();

  const int s = t & 63;
  const int grp = t >> 6;
  const int tb = grp * 16;
  const float* qrow = Qf + ((srow0 + s) * HH + h) * MM;

  float a[16];
#pragma unroll
  for (int j = 0; j < 16; ++j) a[j] = 0.f;
  for (int mc = 0; mc < MM; mc += 16) {
    float qv[16];
#pragma unroll
    for (int i = 0; i < 16; ++i) qv[i] = qrow[mc + i];
#pragma unroll
    for (int j = 0; j < 16; ++j) {
      float p = 0.f;
#pragma unroll
      for (int i = 0; i < 16; ++i) p += qv[i] * KV[tb + j][mc + i];
      a[j] += p;
    }
  }
#pragma unroll
  for (int j = 0; j < 16; ++j) Abuf[s][tb + j] = a[j];
  __syncthreads();

  for (int e = t; e < CHK * DH; e += 256) {
    const int row = e >> 6, d = e & 63;
    KV[row][d] = qkv[(srow0 + row) * QKV_N + 1024 + h * DH + d];
  }
  __syncthreads();

  const int dg = grp * 16;
  float num[16];
#pragma unroll
  for (int j = 0; j < 16; ++j) num[j] = 0.f;
  float den = 0.f;
  for (int tt = 0; tt <= s; ++tt) {
    const float av = Abuf[s][tt];
    den += av;
#pragma unroll
    for (int j = 0; j < 16; ++j) num[j] += av * KV[tt][dg + j];
  }
  if (t < 64) {
    float dq = 0.f;
#pragma unroll
    for (int m = 0; m < MM; ++m) dq += qrow[m] * skp[m];
    denl[s] = den + dq + 1e-6f;
  }
  const float* Sp = Sch + (((size_t)b * HH + h) * NC + c) * (MM * DH);
  for (int m = 0; m < MM; ++m) {
    const float qv = qrow[m];
#pragma unroll
    for (int j = 0; j < 16; ++j) num[j] += qv * Sp[(size_t)m * DH + dg + j];
  }
  __syncthreads();
  const float dinv = 1.f / denl[s];
  unsigned short* op = att + (srow0 + s) * DM + h * DH + dg;
#pragma unroll
  for (int j = 0; j < 16; ++j) op[j] = f2bf(num[j] * dinv);
}

// ---------------------------------------------------------------------------
// out = LayerNorm(a + b) * g + beta; optional bf16 shadow copy
// ---------------------------------------------------------------------------
template<int WBF>
__global__ __launch_bounds__(256)
void add_ln(const float* __restrict__ a, const float* __restrict__ bres,
            const float* __restrict__ g, const float* __restrict__ be,
            float* __restrict__ out, unsigned short* __restrict__ outbf)
{
  const int row = blockIdx.x;
  const int t = threadIdx.x;
  const size_t base = (size_t)row * DM;
  const float x0 = a[base + t] + bres[base + t];
  const float x1 = a[base + t + 256] + bres[base + t + 256];
  __shared__ float red[8];
  float ssum = x0 + x1;
#pragma unroll
  for (int off = 32; off > 0; off >>= 1) ssum += __shfl_xor(ssum, off, 64);
  const int wid = t >> 6, lid = t & 63;
  if (lid == 0) red[wid] = ssum;
  __syncthreads();
  const float mu = (red[0] + red[1] + red[2] + red[3]) * (1.f / DM);
  const float d0 = x0 - mu, d1 = x1 - mu;
  float sv = d0 * d0 + d1 * d1;
#pragma unroll
  for (int off = 32; off > 0; off >>= 1) sv += __shfl_xor(sv, off, 64);
  if (lid == 0) red[4 + wid] = sv;
  __syncthreads();
  const float var = (red[4] + red[5] + red[6] + red[7]) * (1.f / DM);
  const float rs = rsqrtf(var + 1e-5f);
  const float o0 = d0 * rs * g[t]       + be[t];
  const float o1 = d1 * rs * g[t + 256] + be[t + 256];
  out[base + t]       = o0;
  out[base + t + 256] = o1;
  if (WBF) {
    outbf[base + t]       = f2bf(o0);
    outbf[base + t + 256] = f2bf(o1);
  }
}

// ---------------------------------------------------------------------------
// Host-side launch
// ---------------------------------------------------------------------------
extern "C" void kernel_launch(void* const* d_in, const int* in_sizes, int n_in,
                              void* d_out, int out_size, void* d_ws, size_t ws_size,
                              hipStream_t stream)
{
  const float* x      = (const float*)d_in[0];
  const float* Wq     = (const float*)d_in[1];
  const float* bq     = (const float*)d_in[2];
  const float* Wk     = (const float*)d_in[3];
  const float* bk     = (const float*)d_in[4];
  const float* Wv     = (const float*)d_in[5];
  const float* bv     = (const float*)d_in[6];
  const float* Wo     = (const float*)d_in[7];
  const float* bo     = (const float*)d_in[8];
  const float* W1     = (const float*)d_in[9];
  const float* b1     = (const float*)d_in[10];
  const float* W2     = (const float*)d_in[11];
  const float* b2     = (const float*)d_in[12];
  const float* ln1g   = (const float*)d_in[13];
  const float* ln1b   = (const float*)d_in[14];
  const float* ln2g   = (const float*)d_in[15];
  const float* ln2b   = (const float*)d_in[16];
  const float* freqs  = (const float*)d_in[17];
  const float* offs   = (const float*)d_in[18];
  const float* gains  = (const float*)d_in[19];
  const float* noise  = (const float*)d_in[20];
  const float* gate   = (const float*)d_in[21];
  const float* gnoise = (const float*)d_in[22];
  const float* omega  = (const float*)d_in[23];

  float* ws = (float*)d_ws;
  size_t o = 0;
  float* curf = ws + o; o += (size_t)BB * SS * DM;          // 2M
  float* qkvf = ws + o; o += (size_t)BB * SS * QKV_N;       // 6M (aliased later)
  float* Qf   = ws + o; o += (size_t)BB * SS * HH * MM;     // 4M (mid_bf alias)
  float* Kf   = ws + o; o += (size_t)BB * SS * HH * MM;     // 4M
  float* Sch  = ws + o; o += (size_t)BB * HH * NC * MM * DH;// 4M
  float* kch  = ws + o; o += (size_t)BB * HH * NC * MM;
  float* zp   = ws + o; o += (size_t)HH * DH * 2 * NS * RR;
  float* wbf  = ws + o; o += (size_t)HH * DH * RR;
  float* bqkv = ws + o; o += 1536;
  unsigned short* attb  = (unsigned short*)(ws + o); o += (size_t)BB * SS * DM / 2;  // 1M
  unsigned short* h_bf  = (unsigned short*)(ws + o); o += (size_t)BB * SS * DM / 2;  // 1M
  unsigned short* curbf = (unsigned short*)(ws + o); o += (size_t)BB * SS * DM / 2;  // 1M
  unsigned short* Wqkvt = (unsigned short*)(ws + o); o += (size_t)QKV_N * DM / 2;    // 384K
  unsigned short* Wot   = (unsigned short*)(ws + o); o += (size_t)DM * DM / 2;       // 128K
  unsigned short* W1t   = (unsigned short*)(ws + o); o += (size_t)DF * DM / 2;       // 512K
  unsigned short* W2t   = (unsigned short*)(ws + o); o += (size_t)DM * DF / 2;       // 512K

  float* attp = qkvf;                               // aliases (qkv dead by then)
  float* hbuf = qkvf + (size_t)2 * 1024 * 1024;
  float* ybuf = qkvf + (size_t)4 * 1024 * 1024;
  unsigned short* midbf = (unsigned short*)Qf;      // 8M bf16 = 4M floats

  // layer-0 bf16 input
  cvt_bf16<<<(BB * SS * DM / 4 + 255) / 256, 256, 0, stream>>>(x, curbf, BB * SS * DM / 4);

  const int MROWS = BB * SS;  // 4096

  for (int l = 0; l < LL; ++l) {
    const float* in = (l == 0) ? x : curf;

    spe_prep<<<704, 256, 0, stream>>>(gains + (size_t)l * HH * DH * NS,
                                      noise + (size_t)l * HH * DH * 2 * NS * RR,
                                      gate + (size_t)l * HH * DH,
                                      gnoise + (size_t)l * HH * DH * RR, zp, wbf);

    // weight prep (transpose + bf16)
    transpose_bf<<<dim3(16, 16), 256, 0, stream>>>(Wq + (size_t)l * DM * DM, Wqkvt,                    DM, DM);
    transpose_bf<<<dim3(16, 16), 256, 0, stream>>>(Wk + (size_t)l * DM * DM, Wqkvt + (size_t)512 * DM, DM, DM);
    transpose_bf<<<dim3(16, 16), 256, 0, stream>>>(Wv + (size_t)l * DM * DM, Wqkvt + (size_t)1024 * DM,DM, DM);
    transpose_bf<<<dim3(16, 16), 256, 0, stream>>>(Wo + (size_t)l * DM * DM, Wot, DM, DM);
    transpose_bf<<<dim3(64, 16), 256, 0, stream>>>(W1 + (size_t)l * DM * DF, W1t, DM, DF);
    transpose_bf<<<dim3(16, 64), 256, 0, stream>>>(W2 + (size_t)l * DF * DM, W2t, DF, DM);
    pack_bias<<<6, 256, 0, stream>>>(bq + (size_t)l * DM, bk + (size_t)l * DM, bv + (size_t)l * DM, bqkv);

    // fused qkv projection: [4096 x 1536]
    gemm_mfma<0, 0><<<dim3(QKV_N / 128, MROWS / 128), 256, 0, stream>>>(
        curbf, Wqkvt, bqkv, qkvf, (unsigned short*)nullptr, MROWS, QKV_N, DM);

    spe_favor<<<dim3(SS, HH), 256, 0, stream>>>(freqs + (size_t)l * HH * DH * NS,
                                                offs + (size_t)l * HH * DH * NS,
                                                zp, wbf, qkvf,
                                                omega + (size_t)l * DH * (MM / 2), Qf, Kf);

    attn_chunk_sums<<<dim3(NC, HH, BB), 256, 0, stream>>>(Kf, qkvf, Sch, kch);
    attn_scan<<<BB * HH, 256, 0, stream>>>(Sch, kch);
    attn_out<<<dim3(NC, HH, BB), 256, 0, stream>>>(Qf, Kf, qkvf, Sch, kch, attb);

    // output projection
    gemm_mfma<0, 0><<<dim3(DM / 128, MROWS / 128), 256, 0, stream>>>(
        attb, Wot, bo + (size_t)l * DM, attp, (unsigned short*)nullptr, MROWS, DM, DM);

    add_ln<1><<<MROWS, 256, 0, stream>>>(in, attp, ln1g + (size_t)l * DM, ln1b + (size_t)l * DM, hbuf, h_bf);

    // FFN
    gemm_mfma<1, 1><<<dim3(DF / 128, MROWS / 128), 256, 0, stream>>>(
        h_bf, W1t, b1 + (size_t)l * DF, (float*)nullptr, midbf, MROWS, DF, DM);
    gemm_mfma<0, 0><<<dim3(DM / 128, MROWS / 128), 256, 0, stream>>>(
        midbf, W2t, b2 + (size_t)l * DM, ybuf, (unsigned short*)nullptr, MROWS, DM, DF);

    if (l == LL - 1) {
      add_ln<0><<<MROWS, 256, 0, stream>>>(hbuf, ybuf, ln2g + (size_t)l * DM, ln2b + (size_t)l * DM,
                                           (float*)d_out, (unsigned short*)nullptr);
    } else {
      add_ln<1><<<MROWS, 256, 0, stream>>>(hbuf, ybuf, ln2g + (size_t)l * DM, ln2b + (size_t)l * DM,
                                           curf, curbf);
    }
  }
}

// Round 3
// 1191.635 us; speedup vs baseline: 2.1678x; 1.1239x over previous
//
#include <hip/hip_runtime.h>
#include <math.h>

// ---------------------------------------------------------------------------
// Model constants
// ---------------------------------------------------------------------------
#define BB 4
#define SS 1024
#define LL 4
#define HH 8
#define DM 512
#define DF 2048
#define DH 64
#define NS 5
#define RR 32
#define MM 128          // favor feature dims
#define NC 16           // attention chunks
#define CHK 64          // chunk size
#define QKV_N 1536      // packed q|k|v width

#define INV_SQRT10   0.316227766016838f
#define INV_SCALE    0.148650889375340f   // 1/(R*DH)^0.25
#define TEMP_SCALE   0.353553390593274f   // 64^-0.25
#define INV_SQRT_M   0.088388347648318f   // 1/sqrt(128)
#define TWO_PI       6.283185307179586f

typedef __attribute__((ext_vector_type(8))) short bf16x8;
typedef __attribute__((ext_vector_type(4))) float f32x4;

__device__ __forceinline__ unsigned short f2bf(float f) {
  union { float f; unsigned int u; } v; v.f = f;
  unsigned int r = v.u + 0x7FFFu + ((v.u >> 16) & 1u);
  return (unsigned short)(r >> 16);
}

__device__ __forceinline__ void gld_lds16(const unsigned short* g, unsigned short* l) {
  __builtin_amdgcn_global_load_lds((const __attribute__((address_space(1))) void*)g,
                                   (__attribute__((address_space(3))) void*)l,
                                   16, 0, 0);
}

// ---------------------------------------------------------------------------
// bf16 MFMA GEMM, 128x128 tile (m97 structure). A[M][K] bf16, Bt[N][K] bf16.
// ---------------------------------------------------------------------------
template<int RELU, int OUT_BF>
__global__ __launch_bounds__(256)
void gemm_mfma(const unsigned short* __restrict__ A, const unsigned short* __restrict__ Bt,
               const float* __restrict__ bias, float* __restrict__ Cf,
               unsigned short* __restrict__ Cbf, int M, int N, int K)
{
  __shared__ unsigned short As[128 * 32];
  __shared__ unsigned short Bs[128 * 32];
  const int tid  = threadIdx.x;
  const int w    = tid >> 6;
  const int lane = tid & 63;
  const int row0 = blockIdx.y * 128;
  const int col0 = blockIdx.x * 128;
  const int wr = (w >> 1) * 64;
  const int wc = (w & 1) * 64;
  const int c0 = w * 2, c1 = w * 2 + 1;
  const int m0 = c0 * 16 + (lane >> 2);
  const int m1 = c1 * 16 + (lane >> 2);
  const int kA = (lane & 3) * 8;

  f32x4 acc[4][4] = {};

  for (int k0 = 0; k0 < K; k0 += 32) {
    gld_lds16(&A [(size_t)(row0 + m0) * K + k0 + kA], &As[c0 * 512]);
    gld_lds16(&A [(size_t)(row0 + m1) * K + k0 + kA], &As[c1 * 512]);
    gld_lds16(&Bt[(size_t)(col0 + m0) * K + k0 + kA], &Bs[c0 * 512]);
    gld_lds16(&Bt[(size_t)(col0 + m1) * K + k0 + kA], &Bs[c1 * 512]);
    __syncthreads();
    const int rA = wr + (lane & 15);
    const int rB = wc + (lane & 15);
    const int kk = (lane >> 4) * 8;
    bf16x8 af[4], bfr[4];
#pragma unroll
    for (int i = 0; i < 4; ++i) {
      af[i]  = *reinterpret_cast<const bf16x8*>(&As[(rA + i * 16) * 32 + kk]);
      bfr[i] = *reinterpret_cast<const bf16x8*>(&Bs[(rB + i * 16) * 32 + kk]);
    }
#pragma unroll
    for (int mi = 0; mi < 4; ++mi)
#pragma unroll
      for (int ni = 0; ni < 4; ++ni)
        acc[mi][ni] = __builtin_amdgcn_mfma_f32_16x16x32_bf16(af[mi], bfr[ni], acc[mi][ni], 0, 0, 0);
    __syncthreads();
  }
  const int cr = (lane >> 4) * 4;
  const int cc = lane & 15;
#pragma unroll
  for (int mi = 0; mi < 4; ++mi) {
#pragma unroll
    for (int ni = 0; ni < 4; ++ni) {
      const int col = col0 + wc + ni * 16 + cc;
      const float bv = bias[col];
#pragma unroll
      for (int r = 0; r < 4; ++r) {
        const int row = row0 + wr + mi * 16 + cr + r;
        float v = acc[mi][ni][r] + bv;
        if (RELU) v = fmaxf(v, 0.f);
        if (OUT_BF) Cbf[(size_t)row * N + col] = f2bf(v);
        else        Cf [(size_t)row * N + col] = v;
      }
    }
  }
}

// ---------------------------------------------------------------------------
// bf16 MFMA GEMM, 128x64 tile — for small-N GEMMs (2x block parallelism).
// ---------------------------------------------------------------------------
template<int RELU, int OUT_BF>
__global__ __launch_bounds__(256)
void gemm_mfma_n64(const unsigned short* __restrict__ A, const unsigned short* __restrict__ Bt,
                   const float* __restrict__ bias, float* __restrict__ Cf,
                   unsigned short* __restrict__ Cbf, int M, int N, int K)
{
  __shared__ unsigned short As[128 * 32];
  __shared__ unsigned short Bs[64 * 32];
  const int tid  = threadIdx.x;
  const int w    = tid >> 6;
  const int lane = tid & 63;
  const int row0 = blockIdx.y * 128;
  const int col0 = blockIdx.x * 64;
  const int wr = (w >> 1) * 64;
  const int wc = (w & 1) * 32;
  const int c0 = w * 2, c1 = w * 2 + 1;
  const int m0 = c0 * 16 + (lane >> 2);
  const int m1 = c1 * 16 + (lane >> 2);
  const int mb = w * 16 + (lane >> 2);
  const int kA = (lane & 3) * 8;

  f32x4 acc[4][2] = {};

  for (int k0 = 0; k0 < K; k0 += 32) {
    gld_lds16(&A [(size_t)(row0 + m0) * K + k0 + kA], &As[c0 * 512]);
    gld_lds16(&A [(size_t)(row0 + m1) * K + k0 + kA], &As[c1 * 512]);
    gld_lds16(&Bt[(size_t)(col0 + mb) * K + k0 + kA], &Bs[w * 512]);
    __syncthreads();
    const int rA = wr + (lane & 15);
    const int rB = wc + (lane & 15);
    const int kk = (lane >> 4) * 8;
    bf16x8 af[4], bfr[2];
#pragma unroll
    for (int i = 0; i < 4; ++i)
      af[i]  = *reinterpret_cast<const bf16x8*>(&As[(rA + i * 16) * 32 + kk]);
#pragma unroll
    for (int i = 0; i < 2; ++i)
      bfr[i] = *reinterpret_cast<const bf16x8*>(&Bs[(rB + i * 16) * 32 + kk]);
#pragma unroll
    for (int mi = 0; mi < 4; ++mi)
#pragma unroll
      for (int ni = 0; ni < 2; ++ni)
        acc[mi][ni] = __builtin_amdgcn_mfma_f32_16x16x32_bf16(af[mi], bfr[ni], acc[mi][ni], 0, 0, 0);
    __syncthreads();
  }
  const int cr = (lane >> 4) * 4;
  const int cc = lane & 15;
#pragma unroll
  for (int mi = 0; mi < 4; ++mi) {
#pragma unroll
    for (int ni = 0; ni < 2; ++ni) {
      const int col = col0 + wc + ni * 16 + cc;
      const float bv = bias[col];
#pragma unroll
      for (int r = 0; r < 4; ++r) {
        const int row = row0 + wr + mi * 16 + cr + r;
        float v = acc[mi][ni][r] + bv;
        if (RELU) v = fmaxf(v, 0.f);
        if (OUT_BF) Cbf[(size_t)row * N + col] = f2bf(v);
        else        Cf [(size_t)row * N + col] = v;
      }
    }
  }
}

// ---------------------------------------------------------------------------
// Transpose + f32->bf16: W[K][N] -> Wt[N][K]
// ---------------------------------------------------------------------------
__global__ __launch_bounds__(256)
void transpose_bf(const float* __restrict__ W, unsigned short* __restrict__ Wt, int K, int N)
{
  __shared__ float tile[32][33];
  const int k0 = blockIdx.y * 32, n0 = blockIdx.x * 32;
  const int tx = threadIdx.x & 31, ty = threadIdx.x >> 5;
#pragma unroll
  for (int j = 0; j < 4; ++j)
    tile[ty + 8 * j][tx] = W[(size_t)(k0 + ty + 8 * j) * N + n0 + tx];
  __syncthreads();
#pragma unroll
  for (int j = 0; j < 4; ++j)
    Wt[(size_t)(n0 + ty + 8 * j) * K + k0 + tx] = f2bf(tile[tx][ty + 8 * j]);
}

__global__ __launch_bounds__(256)
void pack_bias(const float* __restrict__ bq, const float* __restrict__ bk,
               const float* __restrict__ bv, float* __restrict__ out)
{
  const int i = blockIdx.x * 256 + threadIdx.x;
  if (i < QKV_N) out[i] = (i < 512) ? bq[i] : (i < 1024) ? bk[i - 512] : bv[i - 1024];
}

__global__ __launch_bounds__(256)
void cvt_bf16(const float* __restrict__ in, unsigned short* __restrict__ out, int n4)
{
  const int i = blockIdx.x * 256 + threadIdx.x;
  if (i < n4) {
    const float4 v = reinterpret_cast<const float4*>(in)[i];
    ushort4 o;
    o.x = f2bf(v.x); o.y = f2bf(v.y); o.z = f2bf(v.z); o.w = f2bf(v.w);
    reinterpret_cast<ushort4*>(out)[i] = o;
  }
}

// ---------------------------------------------------------------------------
// SPE precompute
// ---------------------------------------------------------------------------
__global__ __launch_bounds__(256)
void spe_prep(const float* __restrict__ gains, const float* __restrict__ noise,
              const float* __restrict__ gate, const float* __restrict__ gnoise,
              float* __restrict__ zp, float* __restrict__ wb)
{
  const int i = blockIdx.x * 256 + threadIdx.x;
  if (i < HH * DH * 2 * NS * RR) {
    const int hd = i / (2 * NS * RR);
    const int k  = (i >> 5) % (2 * NS);
    const float ga = gains[hd * NS + (k >> 1)];
    const float sp = (ga > 20.f) ? ga : log1pf(expf(ga));
    const float gg = 1.f / (1.f + expf(-gate[hd]));
    const float c1 = sqrtf(fmaxf(1.f - gg, 0.f));
    zp[i] = noise[i] * sp * c1 * (INV_SQRT10 * INV_SCALE);
  } else {
    const int j = i - HH * DH * 2 * NS * RR;
    if (j < HH * DH * RR) {
      const int hd = j >> 5;
      const float gg = 1.f / (1.f + expf(-gate[hd]));
      wb[j] = sqrtf(gg) * gnoise[j] * INV_SCALE;
    }
  }
}

// ---------------------------------------------------------------------------
// spe_xhat: per (s,h) block. Builds qb/kb (bf16, transposed+swizzled), does
// xq/xk = rows @ qb via MFMA, writes xhat (bf16) + half-norms.
// xhat row order: (b*SS+s)*HH+h  (q rows then k rows at +32768).
// ---------------------------------------------------------------------------
__global__ __launch_bounds__(256)
void spe_xhat(const float* __restrict__ freqs, const float* __restrict__ offs,
              const float* __restrict__ zp, const float* __restrict__ wb,
              const float* __restrict__ qkv,
              unsigned short* __restrict__ xhat, float* __restrict__ hn)
{
  const int s = blockIdx.x;
  const int h = blockIdx.y;
  const int t = threadIdx.x;
  const int w = t >> 6;
  const int lane = t & 63;
  __shared__ float omq[DH][2 * NS];
  __shared__ float omk[DH][2 * NS];
  __shared__ unsigned short qbT[64 * 64];   // [col r][k d], swizzled
  __shared__ unsigned short kbT[64 * 64];
  __shared__ unsigned short rQ[16 * 64];    // [row b][k d], swizzled (rows 4-15 garbage)
  __shared__ unsigned short rK[16 * 64];
  __shared__ float hqp[4][8];               // [wave][b: 0-3 q, 4-7 k]

  // step 1: sine phases
  for (int e = t; e < DH * NS; e += 256) {
    const int d = e / NS, ns = e % NS;
    const float fr = 0.5f / (1.f + expf(-freqs[(h * DH + d) * NS + ns]));
    const float phk = TWO_PI * fr * (float)s;
    const float phq = phk + offs[(h * DH + d) * NS + ns];
    float sn, cn;
    sincosf(phk, &sn, &cn);
    omk[d][2 * ns] = cn; omk[d][2 * ns + 1] = sn;
    sincosf(phq, &sn, &cn);
    omq[d][2 * ns] = cn; omq[d][2 * ns + 1] = sn;
  }
  // rows staging (TEMP_SCALE folded in here; linear so equivalent)
  {
    const int b = t >> 6, d = t & 63;
    const size_t idx = ((size_t)b * SS + s) * QKV_N + h * DH + d;
    const int sd = d ^ ((b & 7) << 3);
    rQ[b * 64 + sd] = f2bf(qkv[idx] * TEMP_SCALE);
    rK[b * 64 + sd] = f2bf(qkv[idx + 512] * TEMP_SCALE);
  }
  __syncthreads();
  // step 2: build qbT/kbT (cols 0-31 sine part, 32-63 shared bias)
  for (int e = t; e < DH * RR; e += 256) {
    const int d = e >> 5, r = e & 31;
    const float* zrow = zp + ((size_t)(h * DH + d) * 2 * NS) * RR + r;
    float aq = 0.f, ak2 = 0.f;
#pragma unroll
    for (int kk = 0; kk < 2 * NS; ++kk) {
      const float zv = zrow[(size_t)kk * RR];
      aq  += omq[d][kk] * zv;
      ak2 += omk[d][kk] * zv;
    }
    const int sd = d ^ ((r & 7) << 3);
    qbT[r * 64 + sd] = f2bf(aq);
    kbT[r * 64 + sd] = f2bf(ak2);
    const unsigned short wv = f2bf(wb[(h * DH + d) * RR + r]);
    qbT[(32 + r) * 64 + sd] = wv;
    kbT[(32 + r) * 64 + sd] = wv;
  }
  __syncthreads();
  // step 4: MFMA. wave w -> output cols [16w, 16w+16)
  f32x4 aq = {0.f, 0.f, 0.f, 0.f}, ak = {0.f, 0.f, 0.f, 0.f};
  const int arow = lane & 15;
  const int colr = w * 16 + (lane & 15);
#pragma unroll
  for (int kt = 0; kt < 2; ++kt) {
    const int g = kt * 4 + (lane >> 4);
    const bf16x8 fAq = *reinterpret_cast<const bf16x8*>(&rQ[arow * 64 + ((g ^ (arow & 7)) << 3)]);
    const bf16x8 fAk = *reinterpret_cast<const bf16x8*>(&rK[arow * 64 + ((g ^ (arow & 7)) << 3)]);
    const bf16x8 fBq = *reinterpret_cast<const bf16x8*>(&qbT[colr * 64 + ((g ^ (colr & 7)) << 3)]);
    const bf16x8 fBk = *reinterpret_cast<const bf16x8*>(&kbT[colr * 64 + ((g ^ (colr & 7)) << 3)]);
    aq = __builtin_amdgcn_mfma_f32_16x16x32_bf16(fAq, fBq, aq, 0, 0, 0);
    ak = __builtin_amdgcn_mfma_f32_16x16x32_bf16(fAk, fBk, ak, 0, 0, 0);
  }
  // half-norm partials: reduce over the 16 lanes of this lane-group
  float rq[4], rk2[4];
#pragma unroll
  for (int r = 0; r < 4; ++r) { rq[r] = aq[r] * aq[r]; rk2[r] = ak[r] * ak[r]; }
#pragma unroll
  for (int off = 1; off < 16; off <<= 1) {
#pragma unroll
    for (int r = 0; r < 4; ++r) {
      rq[r]  += __shfl_xor(rq[r],  off, 64);
      rk2[r] += __shfl_xor(rk2[r], off, 64);
    }
  }
  if (lane == 0) {
#pragma unroll
    for (int r = 0; r < 4; ++r) { hqp[w][r] = rq[r]; hqp[w][4 + r] = rk2[r]; }
  }
  // write xhat rows 0-3 (lanes 0-15 hold them: row=reg, col=lane)
  if (lane < 16) {
#pragma unroll
    for (int r = 0; r < 4; ++r) {
      const size_t rowq = ((size_t)r * SS + s) * HH + h;
      xhat[rowq * 64 + w * 16 + lane] = f2bf(aq[r]);
      xhat[(rowq + (size_t)BB * SS * HH) * 64 + w * 16 + lane] = f2bf(ak[r]);
    }
  }
  __syncthreads();
  if (t < 8) {
    const int b = t & 3;
    const int ko = (t >> 2) * 4;
    const float v = 0.5f * (hqp[0][ko + b] + hqp[1][ko + b] + hqp[2][ko + b] + hqp[3][ko + b]);
    const size_t row = ((size_t)b * SS + s) * HH + h + (size_t)(t >> 2) * BB * SS * HH;
    hn[row] = v;
  }
}

// ---------------------------------------------------------------------------
// favor_gemm: u = xhat @ omgT^T (M=65536,N=64,K=64), epilogue exp(+/-u - hn).
// QfKf = contiguous [Qf | Kf], each row -> out[row*128 + m], [.. + 64].
// ---------------------------------------------------------------------------
__global__ __launch_bounds__(256)
void favor_gemm(const unsigned short* __restrict__ xhat, const unsigned short* __restrict__ omgT,
                const float* __restrict__ hn, float* __restrict__ QfKf)
{
  __shared__ unsigned short As[128 * 32];
  __shared__ unsigned short Bs[64 * 32];
  const int tid  = threadIdx.x;
  const int w    = tid >> 6;
  const int lane = tid & 63;
  const int row0 = blockIdx.x * 128;
  const int c0 = w * 2, c1 = w * 2 + 1;
  const int m0 = c0 * 16 + (lane >> 2);
  const int m1 = c1 * 16 + (lane >> 2);
  const int mb = w * 16 + (lane >> 2);
  const int kA = (lane & 3) * 8;

  f32x4 acc[2][4] = {};

#pragma unroll
  for (int k0 = 0; k0 < 64; k0 += 32) {
    gld_lds16(&xhat[(size_t)(row0 + m0) * 64 + k0 + kA], &As[c0 * 512]);
    gld_lds16(&xhat[(size_t)(row0 + m1) * 64 + k0 + kA], &As[c1 * 512]);
    gld_lds16(&omgT[(size_t)mb * 64 + k0 + kA], &Bs[w * 512]);
    __syncthreads();
    const int rA = w * 32 + (lane & 15);
    const int kk = (lane >> 4) * 8;
    bf16x8 af[2], bfr[4];
#pragma unroll
    for (int i = 0; i < 2; ++i)
      af[i]  = *reinterpret_cast<const bf16x8*>(&As[(rA + i * 16) * 32 + kk]);
#pragma unroll
    for (int i = 0; i < 4; ++i)
      bfr[i] = *reinterpret_cast<const bf16x8*>(&Bs[(i * 16 + (lane & 15)) * 32 + kk]);
#pragma unroll
    for (int mi = 0; mi < 2; ++mi)
#pragma unroll
      for (int ni = 0; ni < 4; ++ni)
        acc[mi][ni] = __builtin_amdgcn_mfma_f32_16x16x32_bf16(af[mi], bfr[ni], acc[mi][ni], 0, 0, 0);
    __syncthreads();
  }
  const int cr = (lane >> 4) * 4;
  const int cc = lane & 15;
#pragma unroll
  for (int mi = 0; mi < 2; ++mi) {
#pragma unroll
    for (int r = 0; r < 4; ++r) {
      const size_t row = row0 + w * 32 + mi * 16 + cr + r;
      const float hnv = hn[row];
#pragma unroll
      for (int ni = 0; ni < 4; ++ni) {
        const int m = ni * 16 + cc;
        const float u = acc[mi][ni][r];
        QfKf[row * MM + m]      = expf( u - hnv) * INV_SQRT_M;
        QfKf[row * MM + m + 64] = expf(-u - hnv) * INV_SQRT_M;
      }
    }
  }
}

// ---------------------------------------------------------------------------
// Attention pass A
// ---------------------------------------------------------------------------
__global__ __launch_bounds__(256)
void attn_chunk_sums(const float* __restrict__ Kf, const float* __restrict__ qkv,
                     float* __restrict__ Sch, float* __restrict__ kch)
{
  const int c = blockIdx.x, h = blockIdx.y, b = blockIdx.z;
  const int t = threadIdx.x;
  __shared__ float Kc[CHK][MM];
  __shared__ float Vc[CHK][DH];
  for (int e = t; e < CHK * MM; e += 256) {
    const int row = e >> 7, m = e & 127;
    Kc[row][m] = Kf[(((size_t)b * SS + c * CHK + row) * HH + h) * MM + m];
  }
  for (int e = t; e < CHK * DH; e += 256) {
    const int row = e >> 6, d = e & 63;
    Vc[row][d] = qkv[((size_t)b * SS + c * CHK + row) * QKV_N + 1024 + h * DH + d];
  }
  __syncthreads();
  const int m = t >> 1;
  const int d0 = (t & 1) * 32;
  float acc[32] = {};
  float ks = 0.f;
  for (int r = 0; r < CHK; ++r) {
    const float kv = Kc[r][m];
    ks += kv;
#pragma unroll
    for (int j = 0; j < 32; ++j) acc[j] += kv * Vc[r][d0 + j];
  }
  const size_t base = ((size_t)b * HH + h) * NC + c;
  float* So = Sch + base * (MM * DH) + (size_t)m * DH + d0;
#pragma unroll
  for (int j = 0; j < 32; ++j) So[j] = acc[j];
  if ((t & 1) == 0) kch[base * MM + m] = ks;
}

// ---------------------------------------------------------------------------
// Attention pass B
// ---------------------------------------------------------------------------
__global__ __launch_bounds__(256)
void attn_scan(float* __restrict__ Sch, float* __restrict__ kch)
{
  const int bh = blockIdx.x;
  const int t = threadIdx.x;
  float* base = Sch + (size_t)bh * NC * (MM * DH);
  for (int e = t; e < MM * DH; e += 256) {
    float run = 0.f;
#pragma unroll
    for (int c = 0; c < NC; ++c) {
      const float v = base[(size_t)c * (MM * DH) + e];
      base[(size_t)c * (MM * DH) + e] = run;
      run += v;
    }
  }
  float* kb2 = kch + (size_t)bh * NC * MM;
  if (t < MM) {
    float run = 0.f;
#pragma unroll
    for (int c = 0; c < NC; ++c) {
      const float v = kb2[c * MM + t];
      kb2[c * MM + t] = run;
      run += v;
    }
  }
}

// ---------------------------------------------------------------------------
// Attention pass C (bf16 out)
// ---------------------------------------------------------------------------
__global__ __launch_bounds__(256)
void attn_out(const float* __restrict__ Qf, const float* __restrict__ Kf,
              const float* __restrict__ qkv, const float* __restrict__ Sch,
              const float* __restrict__ kch, unsigned short* __restrict__ att)
{
  const int c = blockIdx.x, h = blockIdx.y, b = blockIdx.z;
  const int t = threadIdx.x;
  __shared__ float KV[CHK][MM];
  __shared__ float Abuf[CHK][CHK + 1];
  __shared__ float denl[CHK];
  __shared__ float skp[MM];
  const size_t srow0 = (size_t)b * SS + c * CHK;

  for (int e = t; e < CHK * MM; e += 256) {
    const int row = e >> 7, m = e & 127;
    KV[row][m] = Kf[((srow0 + row) * HH + h) * MM + m];
  }
  if (t < MM) skp[t] = kch[(((size_t)b * HH + h) * NC + c) * MM + t];
  __syncthreads();

  const int s = t & 63;
  const int grp = t >> 6;
  const int tb = grp * 16;
  const float* qrow = Qf + ((srow0 + s) * HH + h) * MM;

  float a[16];
#pragma unroll
  for (int j = 0; j < 16; ++j) a[j] = 0.f;
  for (int mc = 0; mc < MM; mc += 16) {
    float qv[16];
#pragma unroll
    for (int i = 0; i < 16; ++i) qv[i] = qrow[mc + i];
#pragma unroll
    for (int j = 0; j < 16; ++j) {
      float p = 0.f;
#pragma unroll
      for (int i = 0; i < 16; ++i) p += qv[i] * KV[tb + j][mc + i];
      a[j] += p;
    }
  }
#pragma unroll
  for (int j = 0; j < 16; ++j) Abuf[s][tb + j] = a[j];
  __syncthreads();

  for (int e = t; e < CHK * DH; e += 256) {
    const int row = e >> 6, d = e & 63;
    KV[row][d] = qkv[(srow0 + row) * QKV_N + 1024 + h * DH + d];
  }
  __syncthreads();

  const int dg = grp * 16;
  float num[16];
#pragma unroll
  for (int j = 0; j < 16; ++j) num[j] = 0.f;
  float den = 0.f;
  for (int tt = 0; tt <= s; ++tt) {
    const float av = Abuf[s][tt];
    den += av;
#pragma unroll
    for (int j = 0; j < 16; ++j) num[j] += av * KV[tt][dg + j];
  }
  if (t < 64) {
    float dq = 0.f;
#pragma unroll
    for (int m = 0; m < MM; ++m) dq += qrow[m] * skp[m];
    denl[s] = den + dq + 1e-6f;
  }
  const float* Sp = Sch + (((size_t)b * HH + h) * NC + c) * (MM * DH);
  for (int m = 0; m < MM; ++m) {
    const float qv = qrow[m];
#pragma unroll
    for (int j = 0; j < 16; ++j) num[j] += qv * Sp[(size_t)m * DH + dg + j];
  }
  __syncthreads();
  const float dinv = 1.f / denl[s];
  unsigned short* op = att + (srow0 + s) * DM + h * DH + dg;
#pragma unroll
  for (int j = 0; j < 16; ++j) op[j] = f2bf(num[j] * dinv);
}

// ---------------------------------------------------------------------------
// out = LayerNorm(a + b) * g + beta; optional bf16 shadow
// ---------------------------------------------------------------------------
template<int WBF>
__global__ __launch_bounds__(256)
void add_ln(const float* __restrict__ a, const float* __restrict__ bres,
            const float* __restrict__ g, const float* __restrict__ be,
            float* __restrict__ out, unsigned short* __restrict__ outbf)
{
  const int row = blockIdx.x;
  const int t = threadIdx.x;
  const size_t base = (size_t)row * DM;
  const float x0 = a[base + t] + bres[base + t];
  const float x1 = a[base + t + 256] + bres[base + t + 256];
  __shared__ float red[8];
  float ssum = x0 + x1;
#pragma unroll
  for (int off = 32; off > 0; off >>= 1) ssum += __shfl_xor(ssum, off, 64);
  const int wid = t >> 6, lid = t & 63;
  if (lid == 0) red[wid] = ssum;
  __syncthreads();
  const float mu = (red[0] + red[1] + red[2] + red[3]) * (1.f / DM);
  const float d0 = x0 - mu, d1 = x1 - mu;
  float sv = d0 * d0 + d1 * d1;
#pragma unroll
  for (int off = 32; off > 0; off >>= 1) sv += __shfl_xor(sv, off, 64);
  if (lid == 0) red[4 + wid] = sv;
  __syncthreads();
  const float var = (red[4] + red[5] + red[6] + red[7]) * (1.f / DM);
  const float rs = rsqrtf(var + 1e-5f);
  const float o0 = d0 * rs * g[t]       + be[t];
  const float o1 = d1 * rs * g[t + 256] + be[t + 256];
  out[base + t]       = o0;
  out[base + t + 256] = o1;
  if (WBF) {
    outbf[base + t]       = f2bf(o0);
    outbf[base + t + 256] = f2bf(o1);
  }
}

// ---------------------------------------------------------------------------
// Host-side launch
// ---------------------------------------------------------------------------
extern "C" void kernel_launch(void* const* d_in, const int* in_sizes, int n_in,
                              void* d_out, int out_size, void* d_ws, size_t ws_size,
                              hipStream_t stream)
{
  const float* x      = (const float*)d_in[0];
  const float* Wq     = (const float*)d_in[1];
  const float* bq     = (const float*)d_in[2];
  const float* Wk     = (const float*)d_in[3];
  const float* bk     = (const float*)d_in[4];
  const float* Wv     = (const float*)d_in[5];
  const float* bv     = (const float*)d_in[6];
  const float* Wo     = (const float*)d_in[7];
  const float* bo     = (const float*)d_in[8];
  const float* W1     = (const float*)d_in[9];
  const float* b1     = (const float*)d_in[10];
  const float* W2     = (const float*)d_in[11];
  const float* b2     = (const float*)d_in[12];
  const float* ln1g   = (const float*)d_in[13];
  const float* ln1b   = (const float*)d_in[14];
  const float* ln2g   = (const float*)d_in[15];
  const float* ln2b   = (const float*)d_in[16];
  const float* freqs  = (const float*)d_in[17];
  const float* offs   = (const float*)d_in[18];
  const float* gains  = (const float*)d_in[19];
  const float* noise  = (const float*)d_in[20];
  const float* gate   = (const float*)d_in[21];
  const float* gnoise = (const float*)d_in[22];
  const float* omega  = (const float*)d_in[23];

  float* ws = (float*)d_ws;
  size_t o = 0;
  float* curf = ws + o; o += (size_t)BB * SS * DM;          // 2M
  float* qkvf = ws + o; o += (size_t)BB * SS * QKV_N;       // 6M
  float* Qf   = ws + o; o += (size_t)BB * SS * HH * MM;     // 4M  \ contiguous QfKf
  float* Kf   = ws + o; o += (size_t)BB * SS * HH * MM;     // 4M  /
  float* Sch  = ws + o; o += (size_t)BB * HH * NC * MM * DH;// 4M  (xhat alias)
  float* kch  = ws + o; o += (size_t)BB * HH * NC * MM;
  float* zp   = ws + o; o += (size_t)HH * DH * 2 * NS * RR;
  float* wbf  = ws + o; o += (size_t)HH * DH * RR;
  float* bqkv = ws + o; o += 1536;
  float* hn   = ws + o; o += (size_t)2 * BB * SS * HH;      // 64K floats
  unsigned short* omgT  = (unsigned short*)(ws + o); o += 2048;
  unsigned short* attb  = (unsigned short*)(ws + o); o += (size_t)BB * SS * DM / 2;
  unsigned short* h_bf  = (unsigned short*)(ws + o); o += (size_t)BB * SS * DM / 2;
  unsigned short* curbf = (unsigned short*)(ws + o); o += (size_t)BB * SS * DM / 2;
  unsigned short* Wqkvt = (unsigned short*)(ws + o); o += (size_t)QKV_N * DM / 2;
  unsigned short* Wot   = (unsigned short*)(ws + o); o += (size_t)DM * DM / 2;
  unsigned short* W1t   = (unsigned short*)(ws + o); o += (size_t)DF * DM / 2;
  unsigned short* W2t   = (unsigned short*)(ws + o); o += (size_t)DM * DF / 2;

  float* attp = qkvf;                               // aliases
  float* hbuf = qkvf + (size_t)2 * 1024 * 1024;
  float* ybuf = qkvf + (size_t)4 * 1024 * 1024;
  unsigned short* midbf = (unsigned short*)Qf;      // FFN mid over QfKf (8MB)
  unsigned short* xhat  = (unsigned short*)Sch;     // xhat (8.4MB) over Sch (16MB)

  cvt_bf16<<<(BB * SS * DM / 4 + 255) / 256, 256, 0, stream>>>(x, curbf, BB * SS * DM / 4);

  const int MROWS = BB * SS;  // 4096

  for (int l = 0; l < LL; ++l) {
    const float* in = (l == 0) ? x : curf;

    spe_prep<<<704, 256, 0, stream>>>(gains + (size_t)l * HH * DH * NS,
                                      noise + (size_t)l * HH * DH * 2 * NS * RR,
                                      gate + (size_t)l * HH * DH,
                                      gnoise + (size_t)l * HH * DH * RR, zp, wbf);

    transpose_bf<<<dim3(16, 16), 256, 0, stream>>>(Wq + (size_t)l * DM * DM, Wqkvt,                     DM, DM);
    transpose_bf<<<dim3(16, 16), 256, 0, stream>>>(Wk + (size_t)l * DM * DM, Wqkvt + (size_t)512 * DM,  DM, DM);
    transpose_bf<<<dim3(16, 16), 256, 0, stream>>>(Wv + (size_t)l * DM * DM, Wqkvt + (size_t)1024 * DM, DM, DM);
    transpose_bf<<<dim3(16, 16), 256, 0, stream>>>(Wo + (size_t)l * DM * DM, Wot, DM, DM);
    transpose_bf<<<dim3(64, 16), 256, 0, stream>>>(W1 + (size_t)l * DM * DF, W1t, DM, DF);
    transpose_bf<<<dim3(16, 64), 256, 0, stream>>>(W2 + (size_t)l * DF * DM, W2t, DF, DM);
    transpose_bf<<<dim3(2, 2),   256, 0, stream>>>(omega + (size_t)l * DH * (MM / 2), omgT, DH, MM / 2);
    pack_bias<<<6, 256, 0, stream>>>(bq + (size_t)l * DM, bk + (size_t)l * DM, bv + (size_t)l * DM, bqkv);

    // fused qkv projection (128x64 tiles: 24x32 = 768 blocks)
    gemm_mfma_n64<0, 0><<<dim3(QKV_N / 64, MROWS / 128), 256, 0, stream>>>(
        curbf, Wqkvt, bqkv, qkvf, (unsigned short*)nullptr, MROWS, QKV_N, DM);

    spe_xhat<<<dim3(SS, HH), 256, 0, stream>>>(freqs + (size_t)l * HH * DH * NS,
                                               offs + (size_t)l * HH * DH * NS,
                                               zp, wbf, qkvf, xhat, hn);
    favor_gemm<<<dim3(2 * BB * SS * HH / 128), 256, 0, stream>>>(xhat, omgT, hn, Qf);

    attn_chunk_sums<<<dim3(NC, HH, BB), 256, 0, stream>>>(Kf, qkvf, Sch, kch);
    attn_scan<<<BB * HH, 256, 0, stream>>>(Sch, kch);
    attn_out<<<dim3(NC, HH, BB), 256, 0, stream>>>(Qf, Kf, qkvf, Sch, kch, attb);

    gemm_mfma_n64<0, 0><<<dim3(DM / 64, MROWS / 128), 256, 0, stream>>>(
        attb, Wot, bo + (size_t)l * DM, attp, (unsigned short*)nullptr, MROWS, DM, DM);

    add_ln<1><<<MROWS, 256, 0, stream>>>(in, attp, ln1g + (size_t)l * DM, ln1b + (size_t)l * DM, hbuf, h_bf);

    gemm_mfma<1, 1><<<dim3(DF / 128, MROWS / 128), 256, 0, stream>>>(
        h_bf, W1t, b1 + (size_t)l * DF, (float*)nullptr, midbf, MROWS, DF, DM);
    gemm_mfma_n64<0, 0><<<dim3(DM / 64, MROWS / 128), 256, 0, stream>>>(
        midbf, W2t, b2 + (size_t)l * DM, ybuf, (unsigned short*)nullptr, MROWS, DM, DF);

    if (l == LL - 1) {
      add_ln<0><<<MROWS, 256, 0, stream>>>(hbuf, ybuf, ln2g + (size_t)l * DM, ln2b + (size_t)l * DM,
                                           (float*)d_out, (unsigned short*)nullptr);
    } else {
      add_ln<1><<<MROWS, 256, 0, stream>>>(hbuf, ybuf, ln2g + (size_t)l * DM, ln2b + (size_t)l * DM,
                                           curf, curbf);
    }
  }
}

// Round 4
// 974.824 us; speedup vs baseline: 2.6500x; 1.2224x over previous
//
#include <hip/hip_runtime.h>
#include <math.h>

// ---------------------------------------------------------------------------
// Model constants
// ---------------------------------------------------------------------------
#define BB 4
#define SS 1024
#define LL 4
#define HH 8
#define DM 512
#define DF 2048
#define DH 64
#define NS 5
#define RR 32
#define MM 128          // favor feature dims
#define NC 16           // attention chunks
#define CHK 64          // chunk size
#define QKV_N 1536      // packed q|k|v width

#define INV_SQRT10   0.316227766016838f
#define INV_SCALE    0.148650889375340f   // 1/(R*DH)^0.25
#define TEMP_SCALE   0.353553390593274f   // 64^-0.25
#define INV_SQRT_M   0.088388347648318f   // 1/sqrt(128)
#define TWO_PI       6.283185307179586f

typedef __attribute__((ext_vector_type(8))) short bf16x8;
typedef __attribute__((ext_vector_type(4))) float f32x4;

__device__ __forceinline__ unsigned short f2bf(float f) {
  union { float f; unsigned int u; } v; v.f = f;
  unsigned int r = v.u + 0x7FFFu + ((v.u >> 16) & 1u);
  return (unsigned short)(r >> 16);
}

__device__ __forceinline__ float bf2f(unsigned short u) {
  union { unsigned int u; float f; } v; v.u = (unsigned int)u << 16;
  return v.f;
}

__device__ __forceinline__ void gld_lds16(const unsigned short* g, unsigned short* l) {
  __builtin_amdgcn_global_load_lds((const __attribute__((address_space(1))) void*)g,
                                   (__attribute__((address_space(3))) void*)l,
                                   16, 0, 0);
}

// ---------------------------------------------------------------------------
// bf16 MFMA GEMM, 128x128 tile (m97 structure). A[M][K] bf16, Bt[N][K] bf16.
// ---------------------------------------------------------------------------
template<int RELU, int OUT_BF>
__global__ __launch_bounds__(256)
void gemm_mfma(const unsigned short* __restrict__ A, const unsigned short* __restrict__ Bt,
               const float* __restrict__ bias, float* __restrict__ Cf,
               unsigned short* __restrict__ Cbf, int M, int N, int K)
{
  __shared__ unsigned short As[128 * 32];
  __shared__ unsigned short Bs[128 * 32];
  const int tid  = threadIdx.x;
  const int w    = tid >> 6;
  const int lane = tid & 63;
  const int row0 = blockIdx.y * 128;
  const int col0 = blockIdx.x * 128;
  const int wr = (w >> 1) * 64;
  const int wc = (w & 1) * 64;
  const int c0 = w * 2, c1 = w * 2 + 1;
  const int m0 = c0 * 16 + (lane >> 2);
  const int m1 = c1 * 16 + (lane >> 2);
  const int kA = (lane & 3) * 8;

  f32x4 acc[4][4] = {};

  for (int k0 = 0; k0 < K; k0 += 32) {
    gld_lds16(&A [(size_t)(row0 + m0) * K + k0 + kA], &As[c0 * 512]);
    gld_lds16(&A [(size_t)(row0 + m1) * K + k0 + kA], &As[c1 * 512]);
    gld_lds16(&Bt[(size_t)(col0 + m0) * K + k0 + kA], &Bs[c0 * 512]);
    gld_lds16(&Bt[(size_t)(col0 + m1) * K + k0 + kA], &Bs[c1 * 512]);
    __syncthreads();
    const int rA = wr + (lane & 15);
    const int rB = wc + (lane & 15);
    const int kk = (lane >> 4) * 8;
    bf16x8 af[4], bfr[4];
#pragma unroll
    for (int i = 0; i < 4; ++i) {
      af[i]  = *reinterpret_cast<const bf16x8*>(&As[(rA + i * 16) * 32 + kk]);
      bfr[i] = *reinterpret_cast<const bf16x8*>(&Bs[(rB + i * 16) * 32 + kk]);
    }
#pragma unroll
    for (int mi = 0; mi < 4; ++mi)
#pragma unroll
      for (int ni = 0; ni < 4; ++ni)
        acc[mi][ni] = __builtin_amdgcn_mfma_f32_16x16x32_bf16(af[mi], bfr[ni], acc[mi][ni], 0, 0, 0);
    __syncthreads();
  }
  const int cr = (lane >> 4) * 4;
  const int cc = lane & 15;
#pragma unroll
  for (int mi = 0; mi < 4; ++mi) {
#pragma unroll
    for (int ni = 0; ni < 4; ++ni) {
      const int col = col0 + wc + ni * 16 + cc;
      const float bv = bias[col];
#pragma unroll
      for (int r = 0; r < 4; ++r) {
        const int row = row0 + wr + mi * 16 + cr + r;
        float v = acc[mi][ni][r] + bv;
        if (RELU) v = fmaxf(v, 0.f);
        if (OUT_BF) Cbf[(size_t)row * N + col] = f2bf(v);
        else        Cf [(size_t)row * N + col] = v;
      }
    }
  }
}

// ---------------------------------------------------------------------------
// bf16 MFMA GEMM, 128x64 tile — for small-N GEMMs (2x block parallelism).
// ---------------------------------------------------------------------------
template<int RELU, int OUT_BF>
__global__ __launch_bounds__(256)
void gemm_mfma_n64(const unsigned short* __restrict__ A, const unsigned short* __restrict__ Bt,
                   const float* __restrict__ bias, float* __restrict__ Cf,
                   unsigned short* __restrict__ Cbf, int M, int N, int K)
{
  __shared__ unsigned short As[128 * 32];
  __shared__ unsigned short Bs[64 * 32];
  const int tid  = threadIdx.x;
  const int w    = tid >> 6;
  const int lane = tid & 63;
  const int row0 = blockIdx.y * 128;
  const int col0 = blockIdx.x * 64;
  const int wr = (w >> 1) * 64;
  const int wc = (w & 1) * 32;
  const int c0 = w * 2, c1 = w * 2 + 1;
  const int m0 = c0 * 16 + (lane >> 2);
  const int m1 = c1 * 16 + (lane >> 2);
  const int mb = w * 16 + (lane >> 2);
  const int kA = (lane & 3) * 8;

  f32x4 acc[4][2] = {};

  for (int k0 = 0; k0 < K; k0 += 32) {
    gld_lds16(&A [(size_t)(row0 + m0) * K + k0 + kA], &As[c0 * 512]);
    gld_lds16(&A [(size_t)(row0 + m1) * K + k0 + kA], &As[c1 * 512]);
    gld_lds16(&Bt[(size_t)(col0 + mb) * K + k0 + kA], &Bs[w * 512]);
    __syncthreads();
    const int rA = wr + (lane & 15);
    const int rB = wc + (lane & 15);
    const int kk = (lane >> 4) * 8;
    bf16x8 af[4], bfr[2];
#pragma unroll
    for (int i = 0; i < 4; ++i)
      af[i]  = *reinterpret_cast<const bf16x8*>(&As[(rA + i * 16) * 32 + kk]);
#pragma unroll
    for (int i = 0; i < 2; ++i)
      bfr[i] = *reinterpret_cast<const bf16x8*>(&Bs[(rB + i * 16) * 32 + kk]);
#pragma unroll
    for (int mi = 0; mi < 4; ++mi)
#pragma unroll
      for (int ni = 0; ni < 2; ++ni)
        acc[mi][ni] = __builtin_amdgcn_mfma_f32_16x16x32_bf16(af[mi], bfr[ni], acc[mi][ni], 0, 0, 0);
    __syncthreads();
  }
  const int cr = (lane >> 4) * 4;
  const int cc = lane & 15;
#pragma unroll
  for (int mi = 0; mi < 4; ++mi) {
#pragma unroll
    for (int ni = 0; ni < 2; ++ni) {
      const int col = col0 + wc + ni * 16 + cc;
      const float bv = bias[col];
#pragma unroll
      for (int r = 0; r < 4; ++r) {
        const int row = row0 + wr + mi * 16 + cr + r;
        float v = acc[mi][ni][r] + bv;
        if (RELU) v = fmaxf(v, 0.f);
        if (OUT_BF) Cbf[(size_t)row * N + col] = f2bf(v);
        else        Cf [(size_t)row * N + col] = v;
      }
    }
  }
}

// ---------------------------------------------------------------------------
// Transpose + f32->bf16: W[K][N] -> Wt[N][K]
// ---------------------------------------------------------------------------
__global__ __launch_bounds__(256)
void transpose_bf(const float* __restrict__ W, unsigned short* __restrict__ Wt, int K, int N)
{
  __shared__ float tile[32][33];
  const int k0 = blockIdx.y * 32, n0 = blockIdx.x * 32;
  const int tx = threadIdx.x & 31, ty = threadIdx.x >> 5;
#pragma unroll
  for (int j = 0; j < 4; ++j)
    tile[ty + 8 * j][tx] = W[(size_t)(k0 + ty + 8 * j) * N + n0 + tx];
  __syncthreads();
#pragma unroll
  for (int j = 0; j < 4; ++j)
    Wt[(size_t)(n0 + ty + 8 * j) * K + k0 + tx] = f2bf(tile[tx][ty + 8 * j]);
}

__global__ __launch_bounds__(256)
void pack_bias(const float* __restrict__ bq, const float* __restrict__ bk,
               const float* __restrict__ bv, float* __restrict__ out)
{
  const int i = blockIdx.x * 256 + threadIdx.x;
  if (i < QKV_N) out[i] = (i < 512) ? bq[i] : (i < 1024) ? bk[i - 512] : bv[i - 1024];
}

__global__ __launch_bounds__(256)
void cvt_bf16(const float* __restrict__ in, unsigned short* __restrict__ out, int n4)
{
  const int i = blockIdx.x * 256 + threadIdx.x;
  if (i < n4) {
    const float4 v = reinterpret_cast<const float4*>(in)[i];
    ushort4 o;
    o.x = f2bf(v.x); o.y = f2bf(v.y); o.z = f2bf(v.z); o.w = f2bf(v.w);
    reinterpret_cast<ushort4*>(out)[i] = o;
  }
}

// ---------------------------------------------------------------------------
// SPE precompute
// ---------------------------------------------------------------------------
__global__ __launch_bounds__(256)
void spe_prep(const float* __restrict__ gains, const float* __restrict__ noise,
              const float* __restrict__ gate, const float* __restrict__ gnoise,
              float* __restrict__ zp, float* __restrict__ wb)
{
  const int i = blockIdx.x * 256 + threadIdx.x;
  if (i < HH * DH * 2 * NS * RR) {
    const int hd = i / (2 * NS * RR);
    const int k  = (i >> 5) % (2 * NS);
    const float ga = gains[hd * NS + (k >> 1)];
    const float sp = (ga > 20.f) ? ga : log1pf(expf(ga));
    const float gg = 1.f / (1.f + expf(-gate[hd]));
    const float c1 = sqrtf(fmaxf(1.f - gg, 0.f));
    zp[i] = noise[i] * sp * c1 * (INV_SQRT10 * INV_SCALE);
  } else {
    const int j = i - HH * DH * 2 * NS * RR;
    if (j < HH * DH * RR) {
      const int hd = j >> 5;
      const float gg = 1.f / (1.f + expf(-gate[hd]));
      wb[j] = sqrtf(gg) * gnoise[j] * INV_SCALE;
    }
  }
}

// ---------------------------------------------------------------------------
// spe_xhat: per (s,h) block. Builds qb/kb (bf16, transposed+swizzled), does
// xq/xk = rows @ qb via MFMA, writes xhat (bf16) + half-norms.
// ---------------------------------------------------------------------------
__global__ __launch_bounds__(256)
void spe_xhat(const float* __restrict__ freqs, const float* __restrict__ offs,
              const float* __restrict__ zp, const float* __restrict__ wb,
              const float* __restrict__ qkv,
              unsigned short* __restrict__ xhat, float* __restrict__ hn)
{
  const int s = blockIdx.x;
  const int h = blockIdx.y;
  const int t = threadIdx.x;
  const int w = t >> 6;
  const int lane = t & 63;
  __shared__ float omq[DH][2 * NS];
  __shared__ float omk[DH][2 * NS];
  __shared__ unsigned short qbT[64 * 64];
  __shared__ unsigned short kbT[64 * 64];
  __shared__ unsigned short rQ[16 * 64];
  __shared__ unsigned short rK[16 * 64];
  __shared__ float hqp[4][8];

  for (int e = t; e < DH * NS; e += 256) {
    const int d = e / NS, ns = e % NS;
    const float fr = 0.5f / (1.f + __expf(-freqs[(h * DH + d) * NS + ns]));
    const float phk = TWO_PI * fr * (float)s;
    const float phq = phk + offs[(h * DH + d) * NS + ns];
    float sn, cn;
    __sincosf(phk, &sn, &cn);
    omk[d][2 * ns] = cn; omk[d][2 * ns + 1] = sn;
    __sincosf(phq, &sn, &cn);
    omq[d][2 * ns] = cn; omq[d][2 * ns + 1] = sn;
  }
  {
    const int b = t >> 6, d = t & 63;
    const size_t idx = ((size_t)b * SS + s) * QKV_N + h * DH + d;
    const int sd = d ^ ((b & 7) << 3);
    rQ[b * 64 + sd] = f2bf(qkv[idx] * TEMP_SCALE);
    rK[b * 64 + sd] = f2bf(qkv[idx + 512] * TEMP_SCALE);
  }
  __syncthreads();
  for (int e = t; e < DH * RR; e += 256) {
    const int d = e >> 5, r = e & 31;
    const float* zrow = zp + ((size_t)(h * DH + d) * 2 * NS) * RR + r;
    float aq = 0.f, ak2 = 0.f;
#pragma unroll
    for (int kk = 0; kk < 2 * NS; ++kk) {
      const float zv = zrow[(size_t)kk * RR];
      aq  += omq[d][kk] * zv;
      ak2 += omk[d][kk] * zv;
    }
    const int sd = d ^ ((r & 7) << 3);
    qbT[r * 64 + sd] = f2bf(aq);
    kbT[r * 64 + sd] = f2bf(ak2);
    const unsigned short wv = f2bf(wb[(h * DH + d) * RR + r]);
    qbT[(32 + r) * 64 + sd] = wv;
    kbT[(32 + r) * 64 + sd] = wv;
  }
  __syncthreads();
  f32x4 aq = {0.f, 0.f, 0.f, 0.f}, ak = {0.f, 0.f, 0.f, 0.f};
  const int arow = lane & 15;
  const int colr = w * 16 + (lane & 15);
#pragma unroll
  for (int kt = 0; kt < 2; ++kt) {
    const int g = kt * 4 + (lane >> 4);
    const bf16x8 fAq = *reinterpret_cast<const bf16x8*>(&rQ[arow * 64 + ((g ^ (arow & 7)) << 3)]);
    const bf16x8 fAk = *reinterpret_cast<const bf16x8*>(&rK[arow * 64 + ((g ^ (arow & 7)) << 3)]);
    const bf16x8 fBq = *reinterpret_cast<const bf16x8*>(&qbT[colr * 64 + ((g ^ (colr & 7)) << 3)]);
    const bf16x8 fBk = *reinterpret_cast<const bf16x8*>(&kbT[colr * 64 + ((g ^ (colr & 7)) << 3)]);
    aq = __builtin_amdgcn_mfma_f32_16x16x32_bf16(fAq, fBq, aq, 0, 0, 0);
    ak = __builtin_amdgcn_mfma_f32_16x16x32_bf16(fAk, fBk, ak, 0, 0, 0);
  }
  float rq[4], rk2[4];
#pragma unroll
  for (int r = 0; r < 4; ++r) { rq[r] = aq[r] * aq[r]; rk2[r] = ak[r] * ak[r]; }
#pragma unroll
  for (int off = 1; off < 16; off <<= 1) {
#pragma unroll
    for (int r = 0; r < 4; ++r) {
      rq[r]  += __shfl_xor(rq[r],  off, 64);
      rk2[r] += __shfl_xor(rk2[r], off, 64);
    }
  }
  if (lane == 0) {
#pragma unroll
    for (int r = 0; r < 4; ++r) { hqp[w][r] = rq[r]; hqp[w][4 + r] = rk2[r]; }
  }
  if (lane < 16) {
#pragma unroll
    for (int r = 0; r < 4; ++r) {
      const size_t rowq = ((size_t)r * SS + s) * HH + h;
      xhat[rowq * 64 + w * 16 + lane] = f2bf(aq[r]);
      xhat[(rowq + (size_t)BB * SS * HH) * 64 + w * 16 + lane] = f2bf(ak[r]);
    }
  }
  __syncthreads();
  if (t < 8) {
    const int b = t & 3;
    const int ko = (t >> 2) * 4;
    const float v = 0.5f * (hqp[0][ko + b] + hqp[1][ko + b] + hqp[2][ko + b] + hqp[3][ko + b]);
    const size_t row = ((size_t)b * SS + s) * HH + h + (size_t)(t >> 2) * BB * SS * HH;
    hn[row] = v;
  }
}

// ---------------------------------------------------------------------------
// favor_gemm: u = xhat @ omgT^T, epilogue exp(+/-u - hn).
// ---------------------------------------------------------------------------
__global__ __launch_bounds__(256)
void favor_gemm(const unsigned short* __restrict__ xhat, const unsigned short* __restrict__ omgT,
                const float* __restrict__ hn, float* __restrict__ QfKf)
{
  __shared__ unsigned short As[128 * 32];
  __shared__ unsigned short Bs[64 * 32];
  const int tid  = threadIdx.x;
  const int w    = tid >> 6;
  const int lane = tid & 63;
  const int row0 = blockIdx.x * 128;
  const int c0 = w * 2, c1 = w * 2 + 1;
  const int m0 = c0 * 16 + (lane >> 2);
  const int m1 = c1 * 16 + (lane >> 2);
  const int mb = w * 16 + (lane >> 2);
  const int kA = (lane & 3) * 8;

  f32x4 acc[2][4] = {};

#pragma unroll
  for (int k0 = 0; k0 < 64; k0 += 32) {
    gld_lds16(&xhat[(size_t)(row0 + m0) * 64 + k0 + kA], &As[c0 * 512]);
    gld_lds16(&xhat[(size_t)(row0 + m1) * 64 + k0 + kA], &As[c1 * 512]);
    gld_lds16(&omgT[(size_t)mb * 64 + k0 + kA], &Bs[w * 512]);
    __syncthreads();
    const int rA = w * 32 + (lane & 15);
    const int kk = (lane >> 4) * 8;
    bf16x8 af[2], bfr[4];
#pragma unroll
    for (int i = 0; i < 2; ++i)
      af[i]  = *reinterpret_cast<const bf16x8*>(&As[(rA + i * 16) * 32 + kk]);
#pragma unroll
    for (int i = 0; i < 4; ++i)
      bfr[i] = *reinterpret_cast<const bf16x8*>(&Bs[(i * 16 + (lane & 15)) * 32 + kk]);
#pragma unroll
    for (int mi = 0; mi < 2; ++mi)
#pragma unroll
      for (int ni = 0; ni < 4; ++ni)
        acc[mi][ni] = __builtin_amdgcn_mfma_f32_16x16x32_bf16(af[mi], bfr[ni], acc[mi][ni], 0, 0, 0);
    __syncthreads();
  }
  const int cr = (lane >> 4) * 4;
  const int cc = lane & 15;
#pragma unroll
  for (int mi = 0; mi < 2; ++mi) {
#pragma unroll
    for (int r = 0; r < 4; ++r) {
      const size_t row = row0 + w * 32 + mi * 16 + cr + r;
      const float hnv = hn[row];
#pragma unroll
      for (int ni = 0; ni < 4; ++ni) {
        const int m = ni * 16 + cc;
        const float u = acc[mi][ni][r];
        QfKf[row * MM + m]      = __expf( u - hnv) * INV_SQRT_M;
        QfKf[row * MM + m + 64] = __expf(-u - hnv) * INV_SQRT_M;
      }
    }
  }
}

// ---------------------------------------------------------------------------
// Attention pass A
// ---------------------------------------------------------------------------
__global__ __launch_bounds__(256)
void attn_chunk_sums(const float* __restrict__ Kf, const float* __restrict__ qkv,
                     float* __restrict__ Sch, float* __restrict__ kch)
{
  const int c = blockIdx.x, h = blockIdx.y, b = blockIdx.z;
  const int t = threadIdx.x;
  __shared__ float Kc[CHK][MM];
  __shared__ float Vc[CHK][DH];
  for (int e = t; e < CHK * MM; e += 256) {
    const int row = e >> 7, m = e & 127;
    Kc[row][m] = Kf[(((size_t)b * SS + c * CHK + row) * HH + h) * MM + m];
  }
  for (int e = t; e < CHK * DH; e += 256) {
    const int row = e >> 6, d = e & 63;
    Vc[row][d] = qkv[((size_t)b * SS + c * CHK + row) * QKV_N + 1024 + h * DH + d];
  }
  __syncthreads();
  const int m = t >> 1;
  const int d0 = (t & 1) * 32;
  float acc[32] = {};
  float ks = 0.f;
  for (int r = 0; r < CHK; ++r) {
    const float kv = Kc[r][m];
    ks += kv;
#pragma unroll
    for (int j = 0; j < 32; ++j) acc[j] += kv * Vc[r][d0 + j];
  }
  const size_t base = ((size_t)b * HH + h) * NC + c;
  float* So = Sch + base * (MM * DH) + (size_t)m * DH + d0;
#pragma unroll
  for (int j = 0; j < 32; ++j) So[j] = acc[j];
  if ((t & 1) == 0) kch[base * MM + m] = ks;
}

// ---------------------------------------------------------------------------
// Attention pass B
// ---------------------------------------------------------------------------
__global__ __launch_bounds__(256)
void attn_scan(float* __restrict__ Sch, float* __restrict__ kch)
{
  const int bh = blockIdx.x;
  const int t = threadIdx.x;
  float* base = Sch + (size_t)bh * NC * (MM * DH);
  for (int e = t; e < MM * DH; e += 256) {
    float run = 0.f;
#pragma unroll
    for (int c = 0; c < NC; ++c) {
      const float v = base[(size_t)c * (MM * DH) + e];
      base[(size_t)c * (MM * DH) + e] = run;
      run += v;
    }
  }
  float* kb2 = kch + (size_t)bh * NC * MM;
  if (t < MM) {
    float run = 0.f;
#pragma unroll
    for (int c = 0; c < NC; ++c) {
      const float v = kb2[c * MM + t];
      kb2[c * MM + t] = run;
      run += v;
    }
  }
}

// ---------------------------------------------------------------------------
// Attention pass C — MFMA version.
// S = Qc@Kc^T (64x64, K=128); O = tril(S)@V + Qc@Sprev; den in-register.
// All LDS tiles bf16 with XOR swizzle so fragment reads are ~2-way.
// ---------------------------------------------------------------------------
__global__ __launch_bounds__(256)
void attn_out(const float* __restrict__ Qf, const float* __restrict__ Kf,
              const float* __restrict__ qkv, const float* __restrict__ Sch,
              const float* __restrict__ kch, unsigned short* __restrict__ att)
{
  const int c = blockIdx.x, h = blockIdx.y, b = blockIdx.z;
  const int tid = threadIdx.x;
  const int w = tid >> 6;
  const int lane = tid & 63;
  __shared__ unsigned short Qc[64 * 128];   // [s][m], m ^= (s&15)<<3
  __shared__ unsigned short Sb[64 * 64];    // [s][t], t ^= (s&7)<<3
  __shared__ unsigned short KVU[12288];     // ph1: Kc[t][m]@0; ph2: SpxT[d][m]@0, VT[d][t]@8192
  __shared__ float skp[MM];
  __shared__ float denl[64];

  unsigned short* Kc   = KVU;
  unsigned short* SpxT = KVU;
  unsigned short* VT   = KVU + 8192;

  const size_t srow0 = (size_t)b * SS + c * CHK;
  const float* Qg = Qf + (srow0 * HH + h) * MM;
  const float* Kg = Kf + (srow0 * HH + h) * MM;

  if (tid < MM) skp[tid] = kch[(((size_t)b * HH + h) * NC + c) * MM + tid];

  // stage Qc, Kc (coalesced float4 reads, swizzled ushort4 writes)
  for (int i = tid; i < 2048; i += 256) {
    const int s = i >> 5, m4 = (i & 31) * 4;
    const int sw = m4 ^ ((s & 15) << 3);
    const float4 qv = *reinterpret_cast<const float4*>(&Qg[(size_t)s * (HH * MM) + m4]);
    const float4 kv = *reinterpret_cast<const float4*>(&Kg[(size_t)s * (HH * MM) + m4]);
    ushort4 qo, ko;
    qo.x = f2bf(qv.x); qo.y = f2bf(qv.y); qo.z = f2bf(qv.z); qo.w = f2bf(qv.w);
    ko.x = f2bf(kv.x); ko.y = f2bf(kv.y); ko.z = f2bf(kv.z); ko.w = f2bf(kv.w);
    *reinterpret_cast<ushort4*>(&Qc[s * 128 + sw]) = qo;
    *reinterpret_cast<ushort4*>(&Kc[s * 128 + sw]) = ko;
  }
  // stage VT [d][t] (transposed V)
  for (int i = tid; i < 4096; i += 256) {
    const int d = i & 63, tt = i >> 6;
    const float v = qkv[(srow0 + tt) * QKV_N + 1024 + h * DH + d];
    VT[d * 64 + (tt ^ ((d & 7) << 3))] = f2bf(v);
  }
  __syncthreads();

  // phase 1: S = Qc @ Kc^T  (wave w owns rows 16w..16w+15, all 64 cols)
  const int sA = w * 16 + (lane & 15);
  const int kk = (lane >> 4) * 8;
  f32x4 acc_s[4] = {};
#pragma unroll
  for (int kc = 0; kc < 4; ++kc) {
    const int k = kc * 32 + kk;
    const bf16x8 aq = *reinterpret_cast<const bf16x8*>(&Qc[sA * 128 + (k ^ ((sA & 15) << 3))]);
#pragma unroll
    for (int n = 0; n < 4; ++n) {
      const int tB = n * 16 + (lane & 15);
      const bf16x8 bq = *reinterpret_cast<const bf16x8*>(&Kc[tB * 128 + (k ^ ((tB & 15) << 3))]);
      acc_s[n] = __builtin_amdgcn_mfma_f32_16x16x32_bf16(aq, bq, acc_s[n], 0, 0, 0);
    }
  }
  __syncthreads();   // all Kc reads done; KVU reusable

  // mask + den_intra + write Sb
  {
    const int g = lane >> 4;
    const int tcol = lane & 15;
    float dintra[4] = {0.f, 0.f, 0.f, 0.f};
#pragma unroll
    for (int r = 0; r < 4; ++r) {
      const int s = w * 16 + g * 4 + r;
#pragma unroll
      for (int n = 0; n < 4; ++n) {
        const int t2 = n * 16 + tcol;
        const float v = (t2 <= s) ? acc_s[n][r] : 0.f;
        dintra[r] += v;
        Sb[s * 64 + (t2 ^ ((s & 7) << 3))] = f2bf(v);
      }
    }
#pragma unroll
    for (int off = 1; off < 16; off <<= 1)
#pragma unroll
      for (int r = 0; r < 4; ++r) dintra[r] += __shfl_xor(dintra[r], off, 64);
    if (tcol == 0) {
#pragma unroll
      for (int r = 0; r < 4; ++r) denl[w * 16 + g * 4 + r] = dintra[r];
    }
  }
  // stage SpxT [d][m] (transposed Sprev)
  {
    const float* Sp = Sch + (((size_t)b * HH + h) * NC + c) * (MM * DH);
    for (int i = tid; i < 8192; i += 256) {
      const int d = i & 63, m = i >> 6;
      SpxT[d * 128 + (m ^ ((d & 15) << 3))] = f2bf(Sp[(size_t)m * DH + d]);
    }
  }
  __syncthreads();

  // phase 2: O = tril(S) @ V  +  Qc @ Sprev
  f32x4 acc_o[4] = {};
#pragma unroll
  for (int kc = 0; kc < 2; ++kc) {
    const int k = kc * 32 + kk;
    const bf16x8 as = *reinterpret_cast<const bf16x8*>(&Sb[sA * 64 + (k ^ ((sA & 7) << 3))]);
#pragma unroll
    for (int n = 0; n < 4; ++n) {
      const int dB = n * 16 + (lane & 15);
      const bf16x8 bv = *reinterpret_cast<const bf16x8*>(&VT[dB * 64 + (k ^ ((dB & 7) << 3))]);
      acc_o[n] = __builtin_amdgcn_mfma_f32_16x16x32_bf16(as, bv, acc_o[n], 0, 0, 0);
    }
  }
#pragma unroll
  for (int kc = 0; kc < 4; ++kc) {
    const int k = kc * 32 + kk;
    const bf16x8 aq = *reinterpret_cast<const bf16x8*>(&Qc[sA * 128 + (k ^ ((sA & 15) << 3))]);
#pragma unroll
    for (int n = 0; n < 4; ++n) {
      const int dB = n * 16 + (lane & 15);
      const bf16x8 bs = *reinterpret_cast<const bf16x8*>(&SpxT[dB * 128 + (k ^ ((dB & 15) << 3))]);
      acc_o[n] = __builtin_amdgcn_mfma_f32_16x16x32_bf16(aq, bs, acc_o[n], 0, 0, 0);
    }
  }
  // den_inter = q . skp  (4 lanes per row)
  {
    const int s2 = tid >> 2, part = tid & 3;
    float p = 0.f;
#pragma unroll
    for (int j = 0; j < 32; ++j) {
      const int m = part * 32 + j;
      p += bf2f(Qc[s2 * 128 + (m ^ ((s2 & 15) << 3))]) * skp[m];
    }
    p += __shfl_xor(p, 1, 64);
    p += __shfl_xor(p, 2, 64);
    if (part == 0) denl[s2] += p + 1e-6f;
  }
  __syncthreads();

  // epilogue: divide by den, store bf16
  {
    const int g = lane >> 4;
    const int dcol = lane & 15;
#pragma unroll
    for (int r = 0; r < 4; ++r) {
      const int s = w * 16 + g * 4 + r;
      const float dinv = 1.f / denl[s];
#pragma unroll
      for (int n = 0; n < 4; ++n)
        att[(srow0 + s) * DM + h * DH + n * 16 + dcol] = f2bf(acc_o[n][r] * dinv);
    }
  }
}

// ---------------------------------------------------------------------------
// out = LayerNorm(a + b) * g + beta; optional bf16 shadow
// ---------------------------------------------------------------------------
template<int WBF>
__global__ __launch_bounds__(256)
void add_ln(const float* __restrict__ a, const float* __restrict__ bres,
            const float* __restrict__ g, const float* __restrict__ be,
            float* __restrict__ out, unsigned short* __restrict__ outbf)
{
  const int row = blockIdx.x;
  const int t = threadIdx.x;
  const size_t base = (size_t)row * DM;
  const float x0 = a[base + t] + bres[base + t];
  const float x1 = a[base + t + 256] + bres[base + t + 256];
  __shared__ float red[8];
  float ssum = x0 + x1;
#pragma unroll
  for (int off = 32; off > 0; off >>= 1) ssum += __shfl_xor(ssum, off, 64);
  const int wid = t >> 6, lid = t & 63;
  if (lid == 0) red[wid] = ssum;
  __syncthreads();
  const float mu = (red[0] + red[1] + red[2] + red[3]) * (1.f / DM);
  const float d0 = x0 - mu, d1 = x1 - mu;
  float sv = d0 * d0 + d1 * d1;
#pragma unroll
  for (int off = 32; off > 0; off >>= 1) sv += __shfl_xor(sv, off, 64);
  if (lid == 0) red[4 + wid] = sv;
  __syncthreads();
  const float var = (red[4] + red[5] + red[6] + red[7]) * (1.f / DM);
  const float rs = rsqrtf(var + 1e-5f);
  const float o0 = d0 * rs * g[t]       + be[t];
  const float o1 = d1 * rs * g[t + 256] + be[t + 256];
  out[base + t]       = o0;
  out[base + t + 256] = o1;
  if (WBF) {
    outbf[base + t]       = f2bf(o0);
    outbf[base + t + 256] = f2bf(o1);
  }
}

// ---------------------------------------------------------------------------
// Host-side launch
// ---------------------------------------------------------------------------
extern "C" void kernel_launch(void* const* d_in, const int* in_sizes, int n_in,
                              void* d_out, int out_size, void* d_ws, size_t ws_size,
                              hipStream_t stream)
{
  const float* x      = (const float*)d_in[0];
  const float* Wq     = (const float*)d_in[1];
  const float* bq     = (const float*)d_in[2];
  const float* Wk     = (const float*)d_in[3];
  const float* bk     = (const float*)d_in[4];
  const float* Wv     = (const float*)d_in[5];
  const float* bv     = (const float*)d_in[6];
  const float* Wo     = (const float*)d_in[7];
  const float* bo     = (const float*)d_in[8];
  const float* W1     = (const float*)d_in[9];
  const float* b1     = (const float*)d_in[10];
  const float* W2     = (const float*)d_in[11];
  const float* b2     = (const float*)d_in[12];
  const float* ln1g   = (const float*)d_in[13];
  const float* ln1b   = (const float*)d_in[14];
  const float* ln2g   = (const float*)d_in[15];
  const float* ln2b   = (const float*)d_in[16];
  const float* freqs  = (const float*)d_in[17];
  const float* offs   = (const float*)d_in[18];
  const float* gains  = (const float*)d_in[19];
  const float* noise  = (const float*)d_in[20];
  const float* gate   = (const float*)d_in[21];
  const float* gnoise = (const float*)d_in[22];
  const float* omega  = (const float*)d_in[23];

  float* ws = (float*)d_ws;
  size_t o = 0;
  float* curf = ws + o; o += (size_t)BB * SS * DM;          // 2M
  float* qkvf = ws + o; o += (size_t)BB * SS * QKV_N;       // 6M
  float* Qf   = ws + o; o += (size_t)BB * SS * HH * MM;     // 4M  \ contiguous QfKf
  float* Kf   = ws + o; o += (size_t)BB * SS * HH * MM;     // 4M  /
  float* Sch  = ws + o; o += (size_t)BB * HH * NC * MM * DH;// 4M  (xhat alias)
  float* kch  = ws + o; o += (size_t)BB * HH * NC * MM;
  float* zp   = ws + o; o += (size_t)HH * DH * 2 * NS * RR;
  float* wbf  = ws + o; o += (size_t)HH * DH * RR;
  float* bqkv = ws + o; o += 1536;
  float* hn   = ws + o; o += (size_t)2 * BB * SS * HH;
  unsigned short* omgT  = (unsigned short*)(ws + o); o += 2048;
  unsigned short* attb  = (unsigned short*)(ws + o); o += (size_t)BB * SS * DM / 2;
  unsigned short* h_bf  = (unsigned short*)(ws + o); o += (size_t)BB * SS * DM / 2;
  unsigned short* curbf = (unsigned short*)(ws + o); o += (size_t)BB * SS * DM / 2;
  unsigned short* Wqkvt = (unsigned short*)(ws + o); o += (size_t)QKV_N * DM / 2;
  unsigned short* Wot   = (unsigned short*)(ws + o); o += (size_t)DM * DM / 2;
  unsigned short* W1t   = (unsigned short*)(ws + o); o += (size_t)DF * DM / 2;
  unsigned short* W2t   = (unsigned short*)(ws + o); o += (size_t)DM * DF / 2;

  float* attp = qkvf;
  float* hbuf = qkvf + (size_t)2 * 1024 * 1024;
  float* ybuf = qkvf + (size_t)4 * 1024 * 1024;
  unsigned short* midbf = (unsigned short*)Qf;
  unsigned short* xhat  = (unsigned short*)Sch;

  cvt_bf16<<<(BB * SS * DM / 4 + 255) / 256, 256, 0, stream>>>(x, curbf, BB * SS * DM / 4);

  const int MROWS = BB * SS;  // 4096

  for (int l = 0; l < LL; ++l) {
    const float* in = (l == 0) ? x : curf;

    spe_prep<<<704, 256, 0, stream>>>(gains + (size_t)l * HH * DH * NS,
                                      noise + (size_t)l * HH * DH * 2 * NS * RR,
                                      gate + (size_t)l * HH * DH,
                                      gnoise + (size_t)l * HH * DH * RR, zp, wbf);

    transpose_bf<<<dim3(16, 16), 256, 0, stream>>>(Wq + (size_t)l * DM * DM, Wqkvt,                     DM, DM);
    transpose_bf<<<dim3(16, 16), 256, 0, stream>>>(Wk + (size_t)l * DM * DM, Wqkvt + (size_t)512 * DM,  DM, DM);
    transpose_bf<<<dim3(16, 16), 256, 0, stream>>>(Wv + (size_t)l * DM * DM, Wqkvt + (size_t)1024 * DM, DM, DM);
    transpose_bf<<<dim3(16, 16), 256, 0, stream>>>(Wo + (size_t)l * DM * DM, Wot, DM, DM);
    transpose_bf<<<dim3(64, 16), 256, 0, stream>>>(W1 + (size_t)l * DM * DF, W1t, DM, DF);
    transpose_bf<<<dim3(16, 64), 256, 0, stream>>>(W2 + (size_t)l * DF * DM, W2t, DF, DM);
    transpose_bf<<<dim3(2, 2),   256, 0, stream>>>(omega + (size_t)l * DH * (MM / 2), omgT, DH, MM / 2);
    pack_bias<<<6, 256, 0, stream>>>(bq + (size_t)l * DM, bk + (size_t)l * DM, bv + (size_t)l * DM, bqkv);

    gemm_mfma_n64<0, 0><<<dim3(QKV_N / 64, MROWS / 128), 256, 0, stream>>>(
        curbf, Wqkvt, bqkv, qkvf, (unsigned short*)nullptr, MROWS, QKV_N, DM);

    spe_xhat<<<dim3(SS, HH), 256, 0, stream>>>(freqs + (size_t)l * HH * DH * NS,
                                               offs + (size_t)l * HH * DH * NS,
                                               zp, wbf, qkvf, xhat, hn);
    favor_gemm<<<dim3(2 * BB * SS * HH / 128), 256, 0, stream>>>(xhat, omgT, hn, Qf);

    attn_chunk_sums<<<dim3(NC, HH, BB), 256, 0, stream>>>(Kf, qkvf, Sch, kch);
    attn_scan<<<BB * HH, 256, 0, stream>>>(Sch, kch);
    attn_out<<<dim3(NC, HH, BB), 256, 0, stream>>>(Qf, Kf, qkvf, Sch, kch, attb);

    gemm_mfma_n64<0, 0><<<dim3(DM / 64, MROWS / 128), 256, 0, stream>>>(
        attb, Wot, bo + (size_t)l * DM, attp, (unsigned short*)nullptr, MROWS, DM, DM);

    add_ln<1><<<MROWS, 256, 0, stream>>>(in, attp, ln1g + (size_t)l * DM, ln1b + (size_t)l * DM, hbuf, h_bf);

    gemm_mfma<1, 1><<<dim3(DF / 128, MROWS / 128), 256, 0, stream>>>(
        h_bf, W1t, b1 + (size_t)l * DF, (float*)nullptr, midbf, MROWS, DF, DM);
    gemm_mfma_n64<0, 0><<<dim3(DM / 64, MROWS / 128), 256, 0, stream>>>(
        midbf, W2t, b2 + (size_t)l * DM, ybuf, (unsigned short*)nullptr, MROWS, DM, DF);

    if (l == LL - 1) {
      add_ln<0><<<MROWS, 256, 0, stream>>>(hbuf, ybuf, ln2g + (size_t)l * DM, ln2b + (size_t)l * DM,
                                           (float*)d_out, (unsigned short*)nullptr);
    } else {
      add_ln<1><<<MROWS, 256, 0, stream>>>(hbuf, ybuf, ln2g + (size_t)l * DM, ln2b + (size_t)l * DM,
                                           curf, curbf);
    }
  }
}

// Round 6
// 740.596 us; speedup vs baseline: 3.4881x; 1.3163x over previous
//
#include <hip/hip_runtime.h>
#include <math.h>

// ---------------------------------------------------------------------------
// Model constants
// ---------------------------------------------------------------------------
#define BB 4
#define SS 1024
#define LL 4
#define HH 8
#define DM 512
#define DF 2048
#define DH 64
#define NS 5
#define RR 32
#define MM 128          // favor feature dims
#define NC 16           // attention chunks
#define CHK 64          // chunk size
#define QKV_N 1536      // packed q|k|v width

#define INV_SQRT10   0.316227766016838f
#define INV_SCALE    0.148650889375340f   // 1/(R*DH)^0.25
#define TEMP_SCALE   0.353553390593274f   // 64^-0.25
#define INV_SQRT_M   0.088388347648318f   // 1/sqrt(128)
#define TWO_PI       6.283185307179586f

typedef __attribute__((ext_vector_type(8))) short bf16x8;
typedef __attribute__((ext_vector_type(4))) float f32x4;

__device__ __forceinline__ unsigned short f2bf(float f) {
  union { float f; unsigned int u; } v; v.f = f;
  unsigned int r = v.u + 0x7FFFu + ((v.u >> 16) & 1u);
  return (unsigned short)(r >> 16);
}

__device__ __forceinline__ float bf2f(unsigned short u) {
  union { unsigned int u; float f; } v; v.u = (unsigned int)u << 16;
  return v.f;
}

__device__ __forceinline__ void gld_lds16(const unsigned short* g, unsigned short* l) {
  __builtin_amdgcn_global_load_lds((const __attribute__((address_space(1))) void*)g,
                                   (__attribute__((address_space(3))) void*)l,
                                   16, 0, 0);
}

// ---------------------------------------------------------------------------
// bf16 MFMA GEMM, 128x128 tile. A[M][K] bf16, Bt[N][K] bf16.
// ---------------------------------------------------------------------------
template<int RELU, int OUT_BF>
__global__ __launch_bounds__(256)
void gemm_mfma(const unsigned short* __restrict__ A, const unsigned short* __restrict__ Bt,
               const float* __restrict__ bias, float* __restrict__ Cf,
               unsigned short* __restrict__ Cbf, int M, int N, int K)
{
  __shared__ unsigned short As[128 * 32];
  __shared__ unsigned short Bs[128 * 32];
  const int tid  = threadIdx.x;
  const int w    = tid >> 6;
  const int lane = tid & 63;
  const int row0 = blockIdx.y * 128;
  const int col0 = blockIdx.x * 128;
  const int wr = (w >> 1) * 64;
  const int wc = (w & 1) * 64;
  const int c0 = w * 2, c1 = w * 2 + 1;
  const int m0 = c0 * 16 + (lane >> 2);
  const int m1 = c1 * 16 + (lane >> 2);
  const int kA = (lane & 3) * 8;

  f32x4 acc[4][4] = {};

  for (int k0 = 0; k0 < K; k0 += 32) {
    gld_lds16(&A [(size_t)(row0 + m0) * K + k0 + kA], &As[c0 * 512]);
    gld_lds16(&A [(size_t)(row0 + m1) * K + k0 + kA], &As[c1 * 512]);
    gld_lds16(&Bt[(size_t)(col0 + m0) * K + k0 + kA], &Bs[c0 * 512]);
    gld_lds16(&Bt[(size_t)(col0 + m1) * K + k0 + kA], &Bs[c1 * 512]);
    __syncthreads();
    const int rA = wr + (lane & 15);
    const int rB = wc + (lane & 15);
    const int kk = (lane >> 4) * 8;
    bf16x8 af[4], bfr[4];
#pragma unroll
    for (int i = 0; i < 4; ++i) {
      af[i]  = *reinterpret_cast<const bf16x8*>(&As[(rA + i * 16) * 32 + kk]);
      bfr[i] = *reinterpret_cast<const bf16x8*>(&Bs[(rB + i * 16) * 32 + kk]);
    }
#pragma unroll
    for (int mi = 0; mi < 4; ++mi)
#pragma unroll
      for (int ni = 0; ni < 4; ++ni)
        acc[mi][ni] = __builtin_amdgcn_mfma_f32_16x16x32_bf16(af[mi], bfr[ni], acc[mi][ni], 0, 0, 0);
    __syncthreads();
  }
  const int cr = (lane >> 4) * 4;
  const int cc = lane & 15;
#pragma unroll
  for (int mi = 0; mi < 4; ++mi) {
#pragma unroll
    for (int ni = 0; ni < 4; ++ni) {
      const int col = col0 + wc + ni * 16 + cc;
      const float bv = bias[col];
#pragma unroll
      for (int r = 0; r < 4; ++r) {
        const int row = row0 + wr + mi * 16 + cr + r;
        float v = acc[mi][ni][r] + bv;
        if (RELU) v = fmaxf(v, 0.f);
        if (OUT_BF) Cbf[(size_t)row * N + col] = f2bf(v);
        else        Cf [(size_t)row * N + col] = v;
      }
    }
  }
}

// ---------------------------------------------------------------------------
// bf16 MFMA GEMM, 128x64 tile
// ---------------------------------------------------------------------------
template<int RELU, int OUT_BF>
__global__ __launch_bounds__(256)
void gemm_mfma_n64(const unsigned short* __restrict__ A, const unsigned short* __restrict__ Bt,
                   const float* __restrict__ bias, float* __restrict__ Cf,
                   unsigned short* __restrict__ Cbf, int M, int N, int K)
{
  __shared__ unsigned short As[128 * 32];
  __shared__ unsigned short Bs[64 * 32];
  const int tid  = threadIdx.x;
  const int w    = tid >> 6;
  const int lane = tid & 63;
  const int row0 = blockIdx.y * 128;
  const int col0 = blockIdx.x * 64;
  const int wr = (w >> 1) * 64;
  const int wc = (w & 1) * 32;
  const int c0 = w * 2, c1 = w * 2 + 1;
  const int m0 = c0 * 16 + (lane >> 2);
  const int m1 = c1 * 16 + (lane >> 2);
  const int mb = w * 16 + (lane >> 2);
  const int kA = (lane & 3) * 8;

  f32x4 acc[4][2] = {};

  for (int k0 = 0; k0 < K; k0 += 32) {
    gld_lds16(&A [(size_t)(row0 + m0) * K + k0 + kA], &As[c0 * 512]);
    gld_lds16(&A [(size_t)(row0 + m1) * K + k0 + kA], &As[c1 * 512]);
    gld_lds16(&Bt[(size_t)(col0 + mb) * K + k0 + kA], &Bs[w * 512]);
    __syncthreads();
    const int rA = wr + (lane & 15);
    const int rB = wc + (lane & 15);
    const int kk = (lane >> 4) * 8;
    bf16x8 af[4], bfr[2];
#pragma unroll
    for (int i = 0; i < 4; ++i)
      af[i]  = *reinterpret_cast<const bf16x8*>(&As[(rA + i * 16) * 32 + kk]);
#pragma unroll
    for (int i = 0; i < 2; ++i)
      bfr[i] = *reinterpret_cast<const bf16x8*>(&Bs[(rB + i * 16) * 32 + kk]);
#pragma unroll
    for (int mi = 0; mi < 4; ++mi)
#pragma unroll
      for (int ni = 0; ni < 2; ++ni)
        acc[mi][ni] = __builtin_amdgcn_mfma_f32_16x16x32_bf16(af[mi], bfr[ni], acc[mi][ni], 0, 0, 0);
    __syncthreads();
  }
  const int cr = (lane >> 4) * 4;
  const int cc = lane & 15;
#pragma unroll
  for (int mi = 0; mi < 4; ++mi) {
#pragma unroll
    for (int ni = 0; ni < 2; ++ni) {
      const int col = col0 + wc + ni * 16 + cc;
      const float bv = bias[col];
#pragma unroll
      for (int r = 0; r < 4; ++r) {
        const int row = row0 + wr + mi * 16 + cr + r;
        float v = acc[mi][ni][r] + bv;
        if (RELU) v = fmaxf(v, 0.f);
        if (OUT_BF) Cbf[(size_t)row * N + col] = f2bf(v);
        else        Cf [(size_t)row * N + col] = v;
      }
    }
  }
}

// ---------------------------------------------------------------------------
// Transpose + f32->bf16: W[K][N] -> Wt[N][K], layer via blockIdx.z
// ---------------------------------------------------------------------------
__global__ __launch_bounds__(256)
void transpose_bf(const float* __restrict__ W, unsigned short* __restrict__ Wt, int K, int N,
                  size_t inStride, size_t outStride)
{
  const float* Wl = W + blockIdx.z * inStride;
  unsigned short* Wtl = Wt + blockIdx.z * outStride;
  __shared__ float tile[32][33];
  const int k0 = blockIdx.y * 32, n0 = blockIdx.x * 32;
  const int tx = threadIdx.x & 31, ty = threadIdx.x >> 5;
#pragma unroll
  for (int j = 0; j < 4; ++j)
    tile[ty + 8 * j][tx] = Wl[(size_t)(k0 + ty + 8 * j) * N + n0 + tx];
  __syncthreads();
#pragma unroll
  for (int j = 0; j < 4; ++j)
    Wtl[(size_t)(n0 + ty + 8 * j) * K + k0 + tx] = f2bf(tile[tx][ty + 8 * j]);
}

__global__ __launch_bounds__(256)
void pack_bias(const float* __restrict__ bq, const float* __restrict__ bk,
               const float* __restrict__ bv, float* __restrict__ out)
{
  const int l = blockIdx.y;
  const int i = blockIdx.x * 256 + threadIdx.x;
  if (i < QKV_N)
    out[l * QKV_N + i] = (i < 512) ? bq[l * DM + i] : (i < 1024) ? bk[l * DM + i - 512]
                                                                 : bv[l * DM + i - 1024];
}

__global__ __launch_bounds__(256)
void cvt_bf16(const float* __restrict__ in, unsigned short* __restrict__ out, int n4)
{
  const int i = blockIdx.x * 256 + threadIdx.x;
  if (i < n4) {
    const float4 v = reinterpret_cast<const float4*>(in)[i];
    ushort4 o;
    o.x = f2bf(v.x); o.y = f2bf(v.y); o.z = f2bf(v.z); o.w = f2bf(v.w);
    reinterpret_cast<ushort4*>(out)[i] = o;
  }
}

// ---------------------------------------------------------------------------
// SPE precompute, ALL layers:
//  zpb[l][h][r][k10][d64] bf16, wbb[l][h][r][d] bf16, offcs[l][h][d][ns] (cos,sin)
// ---------------------------------------------------------------------------
__global__ __launch_bounds__(256)
void spe_prep_all(const float* __restrict__ gains, const float* __restrict__ noise,
                  const float* __restrict__ gate, const float* __restrict__ gnoise,
                  const float* __restrict__ offsets,
                  unsigned short* __restrict__ zpb, unsigned short* __restrict__ wbb,
                  float2* __restrict__ offcs)
{
  const int i = blockIdx.x * 256 + threadIdx.x;
  const int NZ = LL * HH * RR * 10 * DH;      // 655360
  const int NW = LL * HH * RR * DH;           // 65536
  const int NO = LL * HH * DH * NS;           // 10240
  if (i < NZ) {
    const int d = i & 63;
    int j = i >> 6;
    const int k = j % 10; j /= 10;
    const int r = j & 31; j >>= 5;
    const int h = j & 7;  const int l = j >> 3;
    const int lhd = (l * HH + h) * DH + d;
    const float ga = gains[lhd * NS + (k >> 1)];
    const float sp = (ga > 20.f) ? ga : log1pf(__expf(ga));
    const float gg = 1.f / (1.f + __expf(-gate[lhd]));
    const float c1 = sqrtf(fmaxf(1.f - gg, 0.f));
    const float nz = noise[((size_t)lhd * 10 + k) * 32 + r];
    zpb[i] = f2bf(nz * sp * c1 * (INV_SQRT10 * INV_SCALE));
  } else if (i < NZ + NW) {
    int j = i - NZ;
    const int d = j & 63; j >>= 6;
    const int r = j & 31; j >>= 5;
    const int h = j & 7;  const int l = j >> 3;
    const int lhd = (l * HH + h) * DH + d;
    const float gg = 1.f / (1.f + __expf(-gate[lhd]));
    wbb[i - NZ] = f2bf(sqrtf(gg) * gnoise[(size_t)lhd * 32 + r] * INV_SCALE);
  } else if (i < NZ + NW + NO) {
    const int j = i - NZ - NW;
    float sn, cn;
    __sincosf(offsets[j], &sn, &cn);
    offcs[j] = make_float2(cn, sn);
  }
}

// ---------------------------------------------------------------------------
// spe_xhat: per (s,h). om_k via sincos, om_q via rotation; qb/kb build with
// coalesced bf16x8 zp loads + conflict-free b128 LDS writes; MFMA xhat.
// ---------------------------------------------------------------------------
__global__ __launch_bounds__(256)
void spe_xhat(const float* __restrict__ freqs, const float2* __restrict__ offcs,
              const unsigned short* __restrict__ zpb, const unsigned short* __restrict__ wbb,
              const float* __restrict__ qkv,
              unsigned short* __restrict__ xhat, float* __restrict__ hn)
{
  const int s = blockIdx.x;
  const int h = blockIdx.y;
  const int t = threadIdx.x;
  const int w = t >> 6;
  const int lane = t & 63;
  __shared__ float omqT[10][64];
  __shared__ float omkT[10][64];
  __shared__ unsigned short qbT[64 * 64];
  __shared__ unsigned short kbT[64 * 64];
  __shared__ unsigned short rQ[16 * 64];
  __shared__ unsigned short rK[16 * 64];
  __shared__ float hqp[4][8];

  // phase A: phases for k (sincos) and q (rotate by precomputed offset sincos)
  for (int e = t; e < DH * NS; e += 256) {
    const int d = e / NS, ns = e - d * NS;
    const float fr = 0.5f / (1.f + __expf(-freqs[(h * DH + d) * NS + ns]));
    float sn, cn;
    __sincosf(TWO_PI * fr * (float)s, &sn, &cn);
    const float2 oc = offcs[(h * DH + d) * NS + ns];
    omkT[2 * ns][d]     = cn;
    omkT[2 * ns + 1][d] = sn;
    omqT[2 * ns][d]     = cn * oc.x - sn * oc.y;
    omqT[2 * ns + 1][d] = sn * oc.x + cn * oc.y;
  }
  // q/k row staging (rows 0-3 real; rows 4-15 zero-filled, consumed by MFMA)
  {
    const int b = t >> 6, d = t & 63;
    const size_t idx = ((size_t)b * SS + s) * QKV_N + h * DH + d;
    const int sd = d ^ ((b & 7) << 3);
    rQ[b * 64 + sd] = f2bf(qkv[idx] * TEMP_SCALE);
    rK[b * 64 + sd] = f2bf(qkv[idx + 512] * TEMP_SCALE);
  }
  for (int i = t; i < 768; i += 256) {   // zero rows 4..15
    rQ[256 + i] = 0;
    rK[256 + i] = 0;
  }
  __syncthreads();
  // phase B: build qbT/kbT. thread = (r = t>>3, d-octet dg = t&7)
  {
    const int r = t >> 3, dg = t & 7, d0 = dg * 8;
    float accq[8] = {}, acck[8] = {};
    const unsigned short* zr = zpb + (size_t)(h * RR + r) * 10 * 64 + d0;
#pragma unroll
    for (int k = 0; k < 10; ++k) {
      const bf16x8 zv = *reinterpret_cast<const bf16x8*>(zr + (size_t)k * 64);
      const float4 oq0 = *reinterpret_cast<const float4*>(&omqT[k][d0]);
      const float4 oq1 = *reinterpret_cast<const float4*>(&omqT[k][d0 + 4]);
      const float4 ok0 = *reinterpret_cast<const float4*>(&omkT[k][d0]);
      const float4 ok1 = *reinterpret_cast<const float4*>(&omkT[k][d0 + 4]);
      float zf[8];
#pragma unroll
      for (int j = 0; j < 8; ++j) zf[j] = bf2f((unsigned short)zv[j]);
      accq[0] += zf[0] * oq0.x; accq[1] += zf[1] * oq0.y;
      accq[2] += zf[2] * oq0.z; accq[3] += zf[3] * oq0.w;
      accq[4] += zf[4] * oq1.x; accq[5] += zf[5] * oq1.y;
      accq[6] += zf[6] * oq1.z; accq[7] += zf[7] * oq1.w;
      acck[0] += zf[0] * ok0.x; acck[1] += zf[1] * ok0.y;
      acck[2] += zf[2] * ok0.z; acck[3] += zf[3] * ok0.w;
      acck[4] += zf[4] * ok1.x; acck[5] += zf[5] * ok1.y;
      acck[6] += zf[6] * ok1.z; acck[7] += zf[7] * ok1.w;
    }
    bf16x8 qv, kv;
#pragma unroll
    for (int j = 0; j < 8; ++j) {
      qv[j] = (short)f2bf(accq[j]);
      kv[j] = (short)f2bf(acck[j]);
    }
    const int sd0 = d0 ^ ((r & 7) << 3);
    *reinterpret_cast<bf16x8*>(&qbT[r * 64 + sd0]) = qv;
    *reinterpret_cast<bf16x8*>(&kbT[r * 64 + sd0]) = kv;
    const bf16x8 wv = *reinterpret_cast<const bf16x8*>(&wbb[(size_t)(h * RR + r) * 64 + d0]);
    *reinterpret_cast<bf16x8*>(&qbT[(32 + r) * 64 + sd0]) = wv;
    *reinterpret_cast<bf16x8*>(&kbT[(32 + r) * 64 + sd0]) = wv;
  }
  __syncthreads();
  // MFMA: xq/xk = rows @ qb/kb
  f32x4 aq = {0.f, 0.f, 0.f, 0.f}, ak = {0.f, 0.f, 0.f, 0.f};
  const int arow = lane & 15;
  const int colr = w * 16 + (lane & 15);
#pragma unroll
  for (int kt = 0; kt < 2; ++kt) {
    const int g = kt * 4 + (lane >> 4);
    const bf16x8 fAq = *reinterpret_cast<const bf16x8*>(&rQ[arow * 64 + ((g ^ (arow & 7)) << 3)]);
    const bf16x8 fAk = *reinterpret_cast<const bf16x8*>(&rK[arow * 64 + ((g ^ (arow & 7)) << 3)]);
    const bf16x8 fBq = *reinterpret_cast<const bf16x8*>(&qbT[colr * 64 + ((g ^ (colr & 7)) << 3)]);
    const bf16x8 fBk = *reinterpret_cast<const bf16x8*>(&kbT[colr * 64 + ((g ^ (colr & 7)) << 3)]);
    aq = __builtin_amdgcn_mfma_f32_16x16x32_bf16(fAq, fBq, aq, 0, 0, 0);
    ak = __builtin_amdgcn_mfma_f32_16x16x32_bf16(fAk, fBk, ak, 0, 0, 0);
  }
  float rq[4], rk2[4];
#pragma unroll
  for (int r = 0; r < 4; ++r) { rq[r] = aq[r] * aq[r]; rk2[r] = ak[r] * ak[r]; }
#pragma unroll
  for (int off = 1; off < 16; off <<= 1) {
#pragma unroll
    for (int r = 0; r < 4; ++r) {
      rq[r]  += __shfl_xor(rq[r],  off, 64);
      rk2[r] += __shfl_xor(rk2[r], off, 64);
    }
  }
  if (lane == 0) {
#pragma unroll
    for (int r = 0; r < 4; ++r) { hqp[w][r] = rq[r]; hqp[w][4 + r] = rk2[r]; }
  }
  if (lane < 16) {
#pragma unroll
    for (int r = 0; r < 4; ++r) {
      const size_t rowq = ((size_t)r * SS + s) * HH + h;
      xhat[rowq * 64 + w * 16 + lane] = f2bf(aq[r]);
      xhat[(rowq + (size_t)BB * SS * HH) * 64 + w * 16 + lane] = f2bf(ak[r]);
    }
  }
  __syncthreads();
  if (t < 8) {
    const int b = t & 3;
    const int ko = (t >> 2) * 4;
    const float v = 0.5f * (hqp[0][ko + b] + hqp[1][ko + b] + hqp[2][ko + b] + hqp[3][ko + b]);
    const size_t row = ((size_t)b * SS + s) * HH + h + (size_t)(t >> 2) * BB * SS * HH;
    hn[row] = v;
  }
}

// ---------------------------------------------------------------------------
// favor_gemm: u = xhat @ omgT^T, epilogue exp(+/-u - hn), bf16 out.
// ---------------------------------------------------------------------------
__global__ __launch_bounds__(256)
void favor_gemm(const unsigned short* __restrict__ xhat, const unsigned short* __restrict__ omgT,
                const float* __restrict__ hn, unsigned short* __restrict__ QfKfB)
{
  __shared__ unsigned short As[128 * 32];
  __shared__ unsigned short Bs[64 * 32];
  const int tid  = threadIdx.x;
  const int w    = tid >> 6;
  const int lane = tid & 63;
  const int row0 = blockIdx.x * 128;
  const int c0 = w * 2, c1 = w * 2 + 1;
  const int m0 = c0 * 16 + (lane >> 2);
  const int m1 = c1 * 16 + (lane >> 2);
  const int mb = w * 16 + (lane >> 2);
  const int kA = (lane & 3) * 8;

  f32x4 acc[2][4] = {};

  for (int k0 = 0; k0 < 64; k0 += 32) {
    gld_lds16(&xhat[(size_t)(row0 + m0) * 64 + k0 + kA], &As[c0 * 512]);
    gld_lds16(&xhat[(size_t)(row0 + m1) * 64 + k0 + kA], &As[c1 * 512]);
    gld_lds16(&omgT[(size_t)mb * 64 + k0 + kA], &Bs[w * 512]);
    __syncthreads();
    const int rA = w * 32 + (lane & 15);
    const int kk = (lane >> 4) * 8;
    bf16x8 af[2], bfr[4];
#pragma unroll
    for (int i = 0; i < 2; ++i)
      af[i]  = *reinterpret_cast<const bf16x8*>(&As[(rA + i * 16) * 32 + kk]);
#pragma unroll
    for (int i = 0; i < 4; ++i)
      bfr[i] = *reinterpret_cast<const bf16x8*>(&Bs[(i * 16 + (lane & 15)) * 32 + kk]);
#pragma unroll
    for (int mi = 0; mi < 2; ++mi)
#pragma unroll
      for (int ni = 0; ni < 4; ++ni)
        acc[mi][ni] = __builtin_amdgcn_mfma_f32_16x16x32_bf16(af[mi], bfr[ni], acc[mi][ni], 0, 0, 0);
    __syncthreads();
  }
  const int cr = (lane >> 4) * 4;
  const int cc = lane & 15;
#pragma unroll
  for (int mi = 0; mi < 2; ++mi) {
#pragma unroll
    for (int r = 0; r < 4; ++r) {
      const size_t row = row0 + w * 32 + mi * 16 + cr + r;
      const float hnv = hn[row];
#pragma unroll
      for (int ni = 0; ni < 4; ++ni) {
        const int m = ni * 16 + cc;
        const float u = acc[mi][ni][r];
        QfKfB[row * MM + m]      = f2bf(__expf( u - hnv) * INV_SQRT_M);
        QfKfB[row * MM + m + 64] = f2bf(__expf(-u - hnv) * INV_SQRT_M);
      }
    }
  }
}

// ---------------------------------------------------------------------------
// Attention pass A — MFMA: Sch[m][d] = K^T V per chunk; kch = col-sums of K.
// ---------------------------------------------------------------------------
__global__ __launch_bounds__(256)
void attn_chunk_sums(const unsigned short* __restrict__ KfB, const float* __restrict__ qkv,
                     float* __restrict__ Sch, float* __restrict__ kch)
{
  const int c = blockIdx.x, h = blockIdx.y, b = blockIdx.z;
  const int tid = threadIdx.x;
  const int w = tid >> 6, lane = tid & 63;
  __shared__ unsigned short KcT[128 * 64];  // [m][t], t ^= (m&7)<<3
  __shared__ unsigned short VT[64 * 64];    // [d][t], t ^= (d&7)<<3
  const size_t srow0 = (size_t)b * SS + c * CHK;

  for (int i = tid; i < 8192; i += 256) {
    const int m = i & 127, t = i >> 7;
    KcT[m * 64 + (t ^ ((m & 7) << 3))] = KfB[((srow0 + t) * HH + h) * MM + m];
  }
  for (int i = tid; i < 4096; i += 256) {
    const int d = i & 63, tt = i >> 6;
    VT[d * 64 + (tt ^ ((d & 7) << 3))] = f2bf(qkv[(srow0 + tt) * QKV_N + 1024 + h * DH + d]);
  }
  __syncthreads();

  const int kk = (lane >> 4) * 8;
  f32x4 acc[2][4] = {};
#pragma unroll
  for (int kc = 0; kc < 2; ++kc) {
    const int k = kc * 32 + kk;
#pragma unroll
    for (int mi = 0; mi < 2; ++mi) {
      const int mA = w * 32 + mi * 16 + (lane & 15);
      const bf16x8 a = *reinterpret_cast<const bf16x8*>(&KcT[mA * 64 + (k ^ ((mA & 7) << 3))]);
#pragma unroll
      for (int ni = 0; ni < 4; ++ni) {
        const int dB = ni * 16 + (lane & 15);
        const bf16x8 bb = *reinterpret_cast<const bf16x8*>(&VT[dB * 64 + (k ^ ((dB & 7) << 3))]);
        acc[mi][ni] = __builtin_amdgcn_mfma_f32_16x16x32_bf16(a, bb, acc[mi][ni], 0, 0, 0);
      }
    }
  }
  const size_t base = (((size_t)b * HH + h) * NC + c);
  float* So = Sch + base * (MM * DH);
  const int cr = (lane >> 4) * 4, cc = lane & 15;
#pragma unroll
  for (int mi = 0; mi < 2; ++mi)
#pragma unroll
    for (int ni = 0; ni < 4; ++ni)
#pragma unroll
      for (int r = 0; r < 4; ++r)
        So[(size_t)(w * 32 + mi * 16 + cr + r) * DH + ni * 16 + cc] = acc[mi][ni][r];
  // kch
  {
    const int m = tid >> 1, half = tid & 1;
    float ks = 0.f;
#pragma unroll
    for (int j = 0; j < 32; ++j) {
      const int t2 = half * 32 + j;
      ks += bf2f(KcT[m * 64 + (t2 ^ ((m & 7) << 3))]);
    }
    ks += __shfl_xor(ks, 1, 64);
    if (half == 0) kch[base * MM + m] = ks;
  }
}

// ---------------------------------------------------------------------------
// Attention pass B: exclusive scan over chunks
// ---------------------------------------------------------------------------
__global__ __launch_bounds__(256)
void attn_scan(float* __restrict__ Sch, float* __restrict__ kch)
{
  const int bh = blockIdx.x, part = blockIdx.y;
  const int t = threadIdx.x;
  float* base = Sch + (size_t)bh * NC * (MM * DH);
  for (int e = part * 1024 + t; e < (part + 1) * 1024; e += 256) {
    float run = 0.f;
#pragma unroll
    for (int c = 0; c < NC; ++c) {
      const float v = base[(size_t)c * (MM * DH) + e];
      base[(size_t)c * (MM * DH) + e] = run;
      run += v;
    }
  }
  if (part == 0 && t < MM) {
    float* kb2 = kch + (size_t)bh * NC * MM;
    float run = 0.f;
#pragma unroll
    for (int c = 0; c < NC; ++c) {
      const float v = kb2[c * MM + t];
      kb2[c * MM + t] = run;
      run += v;
    }
  }
}

// ---------------------------------------------------------------------------
// Attention pass C — MFMA (bf16 Qf/Kf inputs)
// ---------------------------------------------------------------------------
__global__ __launch_bounds__(256)
void attn_out(const unsigned short* __restrict__ QfKfB, const float* __restrict__ qkv,
              const float* __restrict__ Sch, const float* __restrict__ kch,
              unsigned short* __restrict__ att)
{
  const int c = blockIdx.x, h = blockIdx.y, b = blockIdx.z;
  const int tid = threadIdx.x;
  const int w = tid >> 6;
  const int lane = tid & 63;
  __shared__ unsigned short Qc[64 * 128];   // [s][m], m ^= (s&15)<<3
  __shared__ unsigned short Sb[64 * 64];    // [s][t], t ^= (s&7)<<3
  __shared__ unsigned short KVU[12288];     // ph1: Kc; ph2: SpxT@0, VT@8192
  __shared__ float skp[MM];
  __shared__ float denl[64];

  unsigned short* Kc   = KVU;
  unsigned short* SpxT = KVU;
  unsigned short* VT   = KVU + 8192;

  const size_t srow0 = (size_t)b * SS + c * CHK;
  const unsigned short* Qg = QfKfB + (srow0 * HH + h) * MM;
  const unsigned short* Kg = Qg + (size_t)BB * SS * HH * MM;

  if (tid < MM) skp[tid] = kch[(((size_t)b * HH + h) * NC + c) * MM + tid];

  // stage Qc, Kc (bf16x8 reads, swizzled b128 writes)
  for (int i = tid; i < 1024; i += 256) {
    const int s2 = i >> 4, m8 = (i & 15) * 8;
    const int sw = m8 ^ ((s2 & 15) << 3);
    *reinterpret_cast<bf16x8*>(&Qc[s2 * 128 + sw]) =
        *reinterpret_cast<const bf16x8*>(&Qg[(size_t)s2 * (HH * MM) + m8]);
    *reinterpret_cast<bf16x8*>(&Kc[s2 * 128 + sw]) =
        *reinterpret_cast<const bf16x8*>(&Kg[(size_t)s2 * (HH * MM) + m8]);
  }
  for (int i = tid; i < 4096; i += 256) {
    const int d = i & 63, tt = i >> 6;
    const float v = qkv[(srow0 + tt) * QKV_N + 1024 + h * DH + d];
    VT[d * 64 + (tt ^ ((d & 7) << 3))] = f2bf(v);
  }
  __syncthreads();

  // phase 1: S = Qc @ Kc^T
  const int sA = w * 16 + (lane & 15);
  const int kk = (lane >> 4) * 8;
  f32x4 acc_s[4] = {};
#pragma unroll
  for (int kc = 0; kc < 4; ++kc) {
    const int k = kc * 32 + kk;
    const bf16x8 aq = *reinterpret_cast<const bf16x8*>(&Qc[sA * 128 + (k ^ ((sA & 15) << 3))]);
#pragma unroll
    for (int n = 0; n < 4; ++n) {
      const int tB = n * 16 + (lane & 15);
      const bf16x8 bq = *reinterpret_cast<const bf16x8*>(&Kc[tB * 128 + (k ^ ((tB & 15) << 3))]);
      acc_s[n] = __builtin_amdgcn_mfma_f32_16x16x32_bf16(aq, bq, acc_s[n], 0, 0, 0);
    }
  }
  __syncthreads();   // Kc reads done; KVU reusable

  // mask + den_intra + write Sb
  {
    const int g = lane >> 4;
    const int tcol = lane & 15;
    float dintra[4] = {0.f, 0.f, 0.f, 0.f};
#pragma unroll
    for (int r = 0; r < 4; ++r) {
      const int s = w * 16 + g * 4 + r;
#pragma unroll
      for (int n = 0; n < 4; ++n) {
        const int t2 = n * 16 + tcol;
        const float v = (t2 <= s) ? acc_s[n][r] : 0.f;
        dintra[r] += v;
        Sb[s * 64 + (t2 ^ ((s & 7) << 3))] = f2bf(v);
      }
    }
#pragma unroll
    for (int off = 1; off < 16; off <<= 1)
#pragma unroll
      for (int r = 0; r < 4; ++r) dintra[r] += __shfl_xor(dintra[r], off, 64);
    if (tcol == 0) {
#pragma unroll
      for (int r = 0; r < 4; ++r) denl[w * 16 + g * 4 + r] = dintra[r];
    }
  }
  // stage SpxT [d][m]
  {
    const float* Sp = Sch + (((size_t)b * HH + h) * NC + c) * (MM * DH);
    for (int i = tid; i < 8192; i += 256) {
      const int d = i & 63, m = i >> 6;
      SpxT[d * 128 + (m ^ ((d & 15) << 3))] = f2bf(Sp[(size_t)m * DH + d]);
    }
  }
  __syncthreads();

  // phase 2: O = tril(S)@V + Qc@Sprev
  f32x4 acc_o[4] = {};
#pragma unroll
  for (int kc = 0; kc < 2; ++kc) {
    const int k = kc * 32 + kk;
    const bf16x8 as = *reinterpret_cast<const bf16x8*>(&Sb[sA * 64 + (k ^ ((sA & 7) << 3))]);
#pragma unroll
    for (int n = 0; n < 4; ++n) {
      const int dB = n * 16 + (lane & 15);
      const bf16x8 bv = *reinterpret_cast<const bf16x8*>(&VT[dB * 64 + (k ^ ((dB & 7) << 3))]);
      acc_o[n] = __builtin_amdgcn_mfma_f32_16x16x32_bf16(as, bv, acc_o[n], 0, 0, 0);
    }
  }
#pragma unroll
  for (int kc = 0; kc < 4; ++kc) {
    const int k = kc * 32 + kk;
    const bf16x8 aq = *reinterpret_cast<const bf16x8*>(&Qc[sA * 128 + (k ^ ((sA & 15) << 3))]);
#pragma unroll
    for (int n = 0; n < 4; ++n) {
      const int dB = n * 16 + (lane & 15);
      const bf16x8 bs = *reinterpret_cast<const bf16x8*>(&SpxT[dB * 128 + (k ^ ((dB & 15) << 3))]);
      acc_o[n] = __builtin_amdgcn_mfma_f32_16x16x32_bf16(aq, bs, acc_o[n], 0, 0, 0);
    }
  }
  // den_inter = q . skp
  {
    const int s2 = tid >> 2, part = tid & 3;
    float p = 0.f;
#pragma unroll
    for (int j = 0; j < 32; ++j) {
      const int m = part * 32 + j;
      p += bf2f(Qc[s2 * 128 + (m ^ ((s2 & 15) << 3))]) * skp[m];
    }
    p += __shfl_xor(p, 1, 64);
    p += __shfl_xor(p, 2, 64);
    if (part == 0) denl[s2] += p + 1e-6f;
  }
  __syncthreads();

  {
    const int g = lane >> 4;
    const int dcol = lane & 15;
#pragma unroll
    for (int r = 0; r < 4; ++r) {
      const int s = w * 16 + g * 4 + r;
      const float dinv = 1.f / denl[s];
#pragma unroll
      for (int n = 0; n < 4; ++n)
        att[(srow0 + s) * DM + h * DH + n * 16 + dcol] = f2bf(acc_o[n][r] * dinv);
    }
  }
}

// ---------------------------------------------------------------------------
// out = LayerNorm(a + b) * g + beta; optional bf16 shadow
// ---------------------------------------------------------------------------
template<int WBF>
__global__ __launch_bounds__(256)
void add_ln(const float* __restrict__ a, const float* __restrict__ bres,
            const float* __restrict__ g, const float* __restrict__ be,
            float* __restrict__ out, unsigned short* __restrict__ outbf)
{
  const int row = blockIdx.x;
  const int t = threadIdx.x;
  const size_t base = (size_t)row * DM;
  const float x0 = a[base + t] + bres[base + t];
  const float x1 = a[base + t + 256] + bres[base + t + 256];
  __shared__ float red[8];
  float ssum = x0 + x1;
#pragma unroll
  for (int off = 32; off > 0; off >>= 1) ssum += __shfl_xor(ssum, off, 64);
  const int wid = t >> 6, lid = t & 63;
  if (lid == 0) red[wid] = ssum;
  __syncthreads();
  const float mu = (red[0] + red[1] + red[2] + red[3]) * (1.f / DM);
  const float d0 = x0 - mu, d1 = x1 - mu;
  float sv = d0 * d0 + d1 * d1;
#pragma unroll
  for (int off = 32; off > 0; off >>= 1) sv += __shfl_xor(sv, off, 64);
  if (lid == 0) red[4 + wid] = sv;
  __syncthreads();
  const float var = (red[4] + red[5] + red[6] + red[7]) * (1.f / DM);
  const float rs = rsqrtf(var + 1e-5f);
  const float o0 = d0 * rs * g[t]       + be[t];
  const float o1 = d1 * rs * g[t + 256] + be[t + 256];
  out[base + t]       = o0;
  out[base + t + 256] = o1;
  if (WBF) {
    outbf[base + t]       = f2bf(o0);
    outbf[base + t + 256] = f2bf(o1);
  }
}

// ---------------------------------------------------------------------------
// Host-side launch
// ---------------------------------------------------------------------------
extern "C" void kernel_launch(void* const* d_in, const int* in_sizes, int n_in,
                              void* d_out, int out_size, void* d_ws, size_t ws_size,
                              hipStream_t stream)
{
  const float* x      = (const float*)d_in[0];
  const float* Wq     = (const float*)d_in[1];
  const float* bq     = (const float*)d_in[2];
  const float* Wk     = (const float*)d_in[3];
  const float* bk     = (const float*)d_in[4];
  const float* Wv     = (const float*)d_in[5];
  const float* bv     = (const float*)d_in[6];
  const float* Wo     = (const float*)d_in[7];
  const float* bo     = (const float*)d_in[8];
  const float* W1     = (const float*)d_in[9];
  const float* b1     = (const float*)d_in[10];
  const float* W2     = (const float*)d_in[11];
  const float* b2     = (const float*)d_in[12];
  const float* ln1g   = (const float*)d_in[13];
  const float* ln1b   = (const float*)d_in[14];
  const float* ln2g   = (const float*)d_in[15];
  const float* ln2b   = (const float*)d_in[16];
  const float* freqs  = (const float*)d_in[17];
  const float* offs   = (const float*)d_in[18];
  const float* gains  = (const float*)d_in[19];
  const float* noise  = (const float*)d_in[20];
  const float* gate   = (const float*)d_in[21];
  const float* gnoise = (const float*)d_in[22];
  const float* omega  = (const float*)d_in[23];

  float* ws = (float*)d_ws;
  size_t o = 0;
  float* curf = ws + o; o += (size_t)BB * SS * DM;            // 2M f
  float* qkvf = ws + o; o += (size_t)BB * SS * QKV_N;         // 6M f
  float* Sch  = ws + o; o += (size_t)BB * HH * NC * MM * DH;  // 4M f
  float* kch  = ws + o; o += (size_t)BB * HH * NC * MM;
  float* hn   = ws + o; o += (size_t)2 * BB * SS * HH;
  float* bqkv = ws + o; o += (size_t)LL * QKV_N;
  float2* offcs = (float2*)(ws + o); o += (size_t)LL * HH * DH * NS * 2;
  unsigned short* QfKfB = (unsigned short*)(ws + o); o += (size_t)2 * BB * SS * HH * MM / 2; // 16MB
  unsigned short* xhat  = (unsigned short*)(ws + o); o += (size_t)2 * BB * SS * HH * DH / 2; // 8MB (own buffer)
  unsigned short* attb  = (unsigned short*)(ws + o); o += (size_t)BB * SS * DM / 2;
  unsigned short* h_bf  = (unsigned short*)(ws + o); o += (size_t)BB * SS * DM / 2;
  unsigned short* curbf = (unsigned short*)(ws + o); o += (size_t)BB * SS * DM / 2;
  unsigned short* Wqkvt = (unsigned short*)(ws + o); o += (size_t)LL * QKV_N * DM / 2;
  unsigned short* Wot   = (unsigned short*)(ws + o); o += (size_t)LL * DM * DM / 2;
  unsigned short* W1t   = (unsigned short*)(ws + o); o += (size_t)DF * DM / 2;
  unsigned short* W2t   = (unsigned short*)(ws + o); o += (size_t)DM * DF / 2;
  unsigned short* omgT  = (unsigned short*)(ws + o); o += (size_t)LL * 4096 / 2;
  unsigned short* zpb   = (unsigned short*)(ws + o); o += (size_t)LL * HH * RR * 10 * DH / 2;
  unsigned short* wbb   = (unsigned short*)(ws + o); o += (size_t)LL * HH * RR * DH / 2;

  float* attp = qkvf;
  float* hbuf = qkvf + (size_t)2 * 1024 * 1024;
  float* ybuf = qkvf + (size_t)4 * 1024 * 1024;
  unsigned short* midbf = QfKfB;                 // FFN mid over QfKf (16MB, sequential)
  unsigned short* KfB   = QfKfB + (size_t)BB * SS * HH * MM;

  const int MROWS = BB * SS;  // 4096

  cvt_bf16<<<(BB * SS * DM / 4 + 255) / 256, 256, 0, stream>>>(x, curbf, BB * SS * DM / 4);
  spe_prep_all<<<2856, 256, 0, stream>>>(gains, noise, gate, gnoise, offs, zpb, wbb, offcs);
  transpose_bf<<<dim3(16, 16, 4), 256, 0, stream>>>(Wq, Wqkvt,                     DM, DM, (size_t)DM * DM, (size_t)QKV_N * DM);
  transpose_bf<<<dim3(16, 16, 4), 256, 0, stream>>>(Wk, Wqkvt + (size_t)512 * DM,  DM, DM, (size_t)DM * DM, (size_t)QKV_N * DM);
  transpose_bf<<<dim3(16, 16, 4), 256, 0, stream>>>(Wv, Wqkvt + (size_t)1024 * DM, DM, DM, (size_t)DM * DM, (size_t)QKV_N * DM);
  transpose_bf<<<dim3(16, 16, 4), 256, 0, stream>>>(Wo, Wot, DM, DM, (size_t)DM * DM, (size_t)DM * DM);
  transpose_bf<<<dim3(2, 2, 4),   256, 0, stream>>>(omega, omgT, DH, MM / 2, (size_t)DH * (MM / 2), 4096);
  pack_bias<<<dim3(6, 4), 256, 0, stream>>>(bq, bk, bv, bqkv);

  for (int l = 0; l < LL; ++l) {
    const float* in = (l == 0) ? x : curf;

    gemm_mfma_n64<0, 0><<<dim3(QKV_N / 64, MROWS / 128), 256, 0, stream>>>(
        curbf, Wqkvt + (size_t)l * QKV_N * DM, bqkv + (size_t)l * QKV_N,
        qkvf, (unsigned short*)nullptr, MROWS, QKV_N, DM);

    spe_xhat<<<dim3(SS, HH), 256, 0, stream>>>(
        freqs + (size_t)l * HH * DH * NS, offcs + (size_t)l * HH * DH * NS,
        zpb + (size_t)l * HH * RR * 10 * DH, wbb + (size_t)l * HH * RR * DH,
        qkvf, xhat, hn);
    favor_gemm<<<dim3(2 * BB * SS * HH / 128), 256, 0, stream>>>(
        xhat, omgT + (size_t)l * 4096, hn, QfKfB);

    attn_chunk_sums<<<dim3(NC, HH, BB), 256, 0, stream>>>(KfB, qkvf, Sch, kch);
    attn_scan<<<dim3(BB * HH, 8), 256, 0, stream>>>(Sch, kch);
    attn_out<<<dim3(NC, HH, BB), 256, 0, stream>>>(QfKfB, qkvf, Sch, kch, attb);

    gemm_mfma_n64<0, 0><<<dim3(DM / 64, MROWS / 128), 256, 0, stream>>>(
        attb, Wot + (size_t)l * DM * DM, bo + (size_t)l * DM,
        attp, (unsigned short*)nullptr, MROWS, DM, DM);

    add_ln<1><<<MROWS, 256, 0, stream>>>(in, attp, ln1g + (size_t)l * DM, ln1b + (size_t)l * DM, hbuf, h_bf);

    transpose_bf<<<dim3(64, 16, 1), 256, 0, stream>>>(W1 + (size_t)l * DM * DF, W1t, DM, DF, 0, 0);
    gemm_mfma<1, 1><<<dim3(DF / 128, MROWS / 128), 256, 0, stream>>>(
        h_bf, W1t, b1 + (size_t)l * DF, (float*)nullptr, midbf, MROWS, DF, DM);
    transpose_bf<<<dim3(16, 64, 1), 256, 0, stream>>>(W2 + (size_t)l * DF * DM, W2t, DF, DM, 0, 0);
    gemm_mfma_n64<0, 0><<<dim3(DM / 64, MROWS / 128), 256, 0, stream>>>(
        midbf, W2t, b2 + (size_t)l * DM, ybuf, (unsigned short*)nullptr, MROWS, DM, DF);

    if (l == LL - 1) {
      add_ln<0><<<MROWS, 256, 0, stream>>>(hbuf, ybuf, ln2g + (size_t)l * DM, ln2b + (size_t)l * DM,
                                           (float*)d_out, (unsigned short*)nullptr);
    } else {
      add_ln<1><<<MROWS, 256, 0, stream>>>(hbuf, ybuf, ln2g + (size_t)l * DM, ln2b + (size_t)l * DM,
                                           curf, curbf);
    }
  }
}